// Round 18
// baseline (688.499 us; speedup 1.0000x reference)
//
#include <hip/hip_runtime.h>

#define N_NODES 100000
#define N_EDGES 1200000
#define DIM_IN 128
#define DIM_H 64
#define DIM_H2 128
#define DIM_OUT 112
#define N_LAYERS 7

// pre-packed weight sizes (uints), padded strides baked in
#define W1P_SZ 4608  // 128 n * 36 kp-stride (kp<32 valid)
#define W2P_SZ 4352  // 64 n * 68 kp-stride (kp<64 valid)
#define WEP_SZ 4352  // encoder: 64 n * 68 kp-stride (kp<64 valid)
#define WFP_SZ 4032  // final: 112 n * 36 kp-stride (kp<32 valid)

typedef __attribute__((ext_vector_type(8))) short bf16x8;
typedef __attribute__((ext_vector_type(4))) float f32x4;

// bf16 pack/unpack: bf16->f32 is just <<16 (bit ops, no cvt instruction)
__device__ __forceinline__ unsigned bf16rne(float f) {
  unsigned u = __float_as_uint(f);
  return (u + 0x7fffu + ((u >> 16) & 1u)) >> 16;
}
__device__ __forceinline__ unsigned pack2bf(float lo, float hi) {
  return bf16rne(lo) | (bf16rne(hi) << 16);
}
__device__ __forceinline__ float bflo(unsigned p) { return __uint_as_float(p << 16); }
__device__ __forceinline__ float bfhi(unsigned p) { return __uint_as_float(p & 0xffff0000u); }
// raw v_exp_f32 (2^x); __exp2f does not exist in HIP device code (R14 lesson)
__device__ __forceinline__ float exp2r(float x) { return __builtin_amdgcn_exp2f(x); }

// ---------------- preprocessing: CSR build (rank-based, R16-proven) ---------
// NOTE (R17): returning atomicAdd costs ~32B/op at the coherence point;
// sharding by blockIdx&7 changed NOTHING (WRITE 42.1MB identical). The only
// fix would be a radix sort (no atomics). Keeping the simple single-array form.

__global__ void k_zero_i(int* __restrict__ p, int n) {
  int i = blockIdx.x * 256 + threadIdx.x;
  if (i < n) p[i] = 0;
}

__global__ void k_hist(const int* __restrict__ dst, int* __restrict__ counts,
                       int* __restrict__ rank) {
  int e = blockIdx.x * 256 + threadIdx.x;
  if (e < N_EDGES) rank[e] = atomicAdd(&counts[dst[e]], 1);
}

__global__ void k_scan1(const int* __restrict__ counts, int* __restrict__ bsums) {
  __shared__ int sd[256];
  int t = threadIdx.x;
  int i = blockIdx.x * 256 + t;
  sd[t] = (i < N_NODES) ? counts[i] : 0;
  __syncthreads();
  for (int s = 128; s > 0; s >>= 1) {
    if (t < s) sd[t] += sd[t + s];
    __syncthreads();
  }
  if (t == 0) bsums[blockIdx.x] = sd[0];
}

__global__ void k_scan2(int* __restrict__ bsums, int nb) {
  __shared__ int sd[512];
  int t = threadIdx.x;
  int v = (t < nb) ? bsums[t] : 0;
  sd[t] = v;
  __syncthreads();
  for (int o = 1; o < 512; o <<= 1) {
    int add = (t >= o) ? sd[t - o] : 0;
    __syncthreads();
    sd[t] += add;
    __syncthreads();
  }
  if (t < nb) bsums[t] = sd[t] - v;  // exclusive
}

__global__ void k_scan3(const int* __restrict__ counts, const int* __restrict__ bsums,
                        int* __restrict__ offs) {
  __shared__ int sd[256];
  int t = threadIdx.x;
  int i = blockIdx.x * 256 + t;
  int v = (i < N_NODES) ? counts[i] : 0;
  sd[t] = v;
  __syncthreads();
  for (int o = 1; o < 256; o <<= 1) {
    int add = (t >= o) ? sd[t - o] : 0;
    __syncthreads();
    sd[t] += add;
    __syncthreads();
  }
  int excl = sd[t] - v + bsums[blockIdx.x];
  if (i < N_NODES) offs[i] = excl;
  if (i == N_NODES - 1) offs[N_NODES] = excl + v;  // = E
}

// atomic-free scatter: position = offs[dst] + rank.
__global__ void k_scatter(const int* __restrict__ src, const int* __restrict__ dst,
                          const int* __restrict__ rank, const int* __restrict__ offs,
                          int* __restrict__ ssrc) {
  int e = blockIdx.x * 256 + threadIdx.x;
  if (e < N_EDGES) {
    int p = offs[dst[e]] + rank[e];
    ssrc[p] = src[e];
  }
}

// ---------------- weight pre-pack (once per launch) ----------------

__global__ void k_prepack(const float* __restrict__ W1, const float* __restrict__ W2,
                          unsigned* __restrict__ W1p, unsigned* __restrict__ W2p) {
  int L = blockIdx.y;
  const float* w1 = W1 + (size_t)L * DIM_H * DIM_H2;
  const float* w2 = W2 + (size_t)L * DIM_H2 * DIM_H;
  unsigned* o1 = W1p + (size_t)L * W1P_SZ;
  unsigned* o2 = W2p + (size_t)L * W2P_SZ;
  for (int i = blockIdx.x * 256 + threadIdx.x; i < W1P_SZ; i += gridDim.x * 256) {
    int n = i / 36, kp = i - n * 36;
    o1[i] = (kp < 32) ? pack2bf(w1[(size_t)(2 * kp) * DIM_H2 + n],
                                w1[(size_t)(2 * kp + 1) * DIM_H2 + n]) : 0u;
  }
  for (int i = blockIdx.x * 256 + threadIdx.x; i < W2P_SZ; i += gridDim.x * 256) {
    int n = i / 68, kp = i - n * 68;
    o2[i] = (kp < 64) ? pack2bf(w2[(size_t)(2 * kp) * DIM_H + n],
                                w2[(size_t)(2 * kp + 1) * DIM_H + n]) : 0u;
  }
}

__global__ void k_prepack_enc(const float* __restrict__ W, unsigned* __restrict__ Wp) {
  for (int i = blockIdx.x * 256 + threadIdx.x; i < WEP_SZ; i += gridDim.x * 256) {
    int n = i / 68, kp = i - n * 68;
    Wp[i] = (kp < 64) ? pack2bf(W[(size_t)(2 * kp) * DIM_H + n],
                                W[(size_t)(2 * kp + 1) * DIM_H + n]) : 0u;
  }
}

__global__ void k_prepack_fin(const float* __restrict__ W, unsigned* __restrict__ Wp) {
  for (int i = blockIdx.x * 256 + threadIdx.x; i < WFP_SZ; i += gridDim.x * 256) {
    int n = i / 36, kp = i - n * 36;
    Wp[i] = (kp < 32) ? pack2bf(W[(size_t)(2 * kp) * DIM_OUT + n],
                                W[(size_t)(2 * kp + 1) * DIM_OUT + n]) : 0u;
  }
}

// ---------------- encoder via MFMA: hBf = bf16(x @ enc_W + enc_b) ----------
// R12-proven, unchanged.

__global__ __launch_bounds__(256, 2) void k_encoder(const float* __restrict__ x,
                                                    const unsigned* __restrict__ Wp,
                                                    const float* __restrict__ bias,
                                                    unsigned short* __restrict__ hBf) {
  __shared__ __attribute__((aligned(16))) unsigned sW[WEP_SZ];    // 17.4KB [n<64][kp<64] s68
  __shared__ __attribute__((aligned(16))) unsigned sxp[32 * 68];  // 8.7KB [row][kp<64] s68
  int t = threadIdx.x;
  int node0 = blockIdx.x * 32;
  int w = t >> 6, lane = t & 63;
  int fr = lane & 15, fq = lane >> 4;
  const uint4* wv4 = (const uint4*)Wp;
  for (int i = t; i < WEP_SZ / 4; i += 256) *(uint4*)&sW[i * 4] = wv4[i];
  for (int i = t; i < 2048; i += 256) {  // 32 rows x 64 kp
    int row = i >> 6, kp = i & 63;
    float2 xv = *(const float2*)&x[(size_t)(node0 + row) * DIM_IN + 2 * kp];
    sxp[row * 68 + kp] = pack2bf(xv.x, xv.y);
  }
  __syncthreads();
  f32x4 acc0 = {0.f, 0.f, 0.f, 0.f}, acc1 = acc0;
#pragma unroll
  for (int s = 0; s < 4; s++) {
    int kp0 = s * 16 + fq * 4;
    bf16x8 a0 = *(const bf16x8*)&sxp[fr * 68 + kp0];
    bf16x8 a1 = *(const bf16x8*)&sxp[(16 + fr) * 68 + kp0];
    bf16x8 wf = *(const bf16x8*)&sW[(w * 16 + fr) * 68 + kp0];
    acc0 = __builtin_amdgcn_mfma_f32_16x16x32_bf16(a0, wf, acc0, 0, 0, 0);
    acc1 = __builtin_amdgcn_mfma_f32_16x16x32_bf16(a1, wf, acc1, 0, 0, 0);
  }
  float bv = bias[w * 16 + fr];
#pragma unroll
  for (int r = 0; r < 4; r++) {
    hBf[(size_t)(node0 + fq * 4 + r) * DIM_H + w * 16 + fr] =
        (unsigned short)bf16rne(acc0[r] + bv);
    hBf[(size_t)(node0 + 16 + fq * 4 + r) * DIM_H + w * 16 + fr] =
        (unsigned short)bf16rne(acc1[r] + bv);
  }
}

// ---------------- FUSED GENConv layer: edge-agg + MsgNorm + MFMA MLP --------
// Wave-autonomous, BARRIER-FREE (R8's fused failure was barrier+40KB-LDS
// occupancy; this has neither). Wave owns 16 nodes:
//  phase E: 8 node-pairs, half-wave per node, R17-proven lean edge loop;
//           m -> pack2bf -> wave-private LDS X-scratch (cross-lane LDS reads
//           after program-ordered writes: same no-barrier idiom as the U
//           scratch, proven in R13-R17's k_mlp).
//  phase M: R13-proven MLP (GEMM1 from X-scratch, LN, U-scratch, GEMM2,
//           epilogue with residual + fused prenorm).
// rIn/rOut MUST differ (host ping-pongs rA/rB): waves gather from remote
// nodes of rIn while writing own nodes of rOut.

template <int RELU>
__global__ __launch_bounds__(256, 2) void k_layer(const unsigned* __restrict__ xin32,
                                                  const int* __restrict__ ssrc,
                                                  const int* __restrict__ offs,
                                                  const float* __restrict__ t_arr,
                                                  const float* __restrict__ sc_arr,
                                                  int layer,
                                                  float* __restrict__ h,
                                                  unsigned short* __restrict__ rnext,
                                                  const unsigned* __restrict__ W1p,
                                                  const float* __restrict__ b1,
                                                  const float* __restrict__ g1,
                                                  const float* __restrict__ bb1,
                                                  const unsigned* __restrict__ W2p,
                                                  const float* __restrict__ b2,
                                                  const float* __restrict__ gn,
                                                  const float* __restrict__ bn,
                                                  int residual) {
  __shared__ unsigned sxw[4][16 * 36];        // 9.2KB: X bf16-pairs [row][kp<32] s36
  __shared__ unsigned short scr[4][16][136];  // 17.4KB: U bf16 [row][c<128] s136
  int t = threadIdx.x;
  int w = t >> 6, lane = t & 63;
  int wid = blockIdx.x * 4 + w;
  if (wid >= N_NODES / 16) return;  // 6250 waves
  int node0 = wid * 16;
  int fr = lane & 15, fq = lane >> 4;
  int half = lane >> 5, cl = lane & 31;

  // ---- phase E: edge aggregation + MsgNorm for own 16 nodes ----
  {
    float c2 = t_arr[layer] * 1.4426950408889634f;  // t * log2(e)
    float sc = sc_arr[layer];
    unsigned cl4 = cl << 2;
    const char* xbase = (const char*)xin32;
#pragma unroll 1
    for (int p = 0; p < 8; p++) {
      int v = node0 + 2 * p + half;
      int beg = offs[v], end = offs[v + 1];
      unsigned xp = *(const unsigned*)(xbase + (((unsigned)v << 7) + cl4));
      float xv0 = bflo(xp), xv1 = bfhi(xp);
      float D0 = 0.f, S0 = 0.f, D1 = 0.f, S1 = 0.f;
      float D2 = 0.f, S2 = 0.f, D3 = 0.f, S3 = 0.f;
      float D4 = 0.f, S4 = 0.f, D5 = 0.f, S5 = 0.f;
      float D6 = 0.f, S6 = 0.f, D7 = 0.f, S7 = 0.f;
      int e = beg;
#define CH(u, lo, hi)                              \
  float lo = RELU ? fmaxf(bflo(u), 0.f) : bflo(u); \
  float hi = RELU ? fmaxf(bfhi(u), 0.f) : bfhi(u);
      for (; e + 7 < end; e += 8) {
        unsigned o0 = ((unsigned)ssrc[e] << 7) + cl4;
        unsigned o1 = ((unsigned)ssrc[e + 1] << 7) + cl4;
        unsigned o2 = ((unsigned)ssrc[e + 2] << 7) + cl4;
        unsigned o3 = ((unsigned)ssrc[e + 3] << 7) + cl4;
        unsigned o4 = ((unsigned)ssrc[e + 4] << 7) + cl4;
        unsigned o5 = ((unsigned)ssrc[e + 5] << 7) + cl4;
        unsigned o6 = ((unsigned)ssrc[e + 6] << 7) + cl4;
        unsigned o7 = ((unsigned)ssrc[e + 7] << 7) + cl4;
        unsigned u0 = *(const unsigned*)(xbase + o0);
        unsigned u1 = *(const unsigned*)(xbase + o1);
        unsigned u2 = *(const unsigned*)(xbase + o2);
        unsigned u3 = *(const unsigned*)(xbase + o3);
        unsigned u4 = *(const unsigned*)(xbase + o4);
        unsigned u5 = *(const unsigned*)(xbase + o5);
        unsigned u6 = *(const unsigned*)(xbase + o6);
        unsigned u7 = *(const unsigned*)(xbase + o7);
        CH(u0, a0, a1) CH(u1, b0, b1) CH(u2, g0, g1) CH(u3, h0, h1)
        CH(u4, i0, i1) CH(u5, j0, j1) CH(u6, k0, k1) CH(u7, l0, l1)
        float ea0 = exp2r(c2 * a0), ea1 = exp2r(c2 * a1);
        float eb0 = exp2r(c2 * b0), eb1 = exp2r(c2 * b1);
        float eg0 = exp2r(c2 * g0), eg1 = exp2r(c2 * g1);
        float eh0 = exp2r(c2 * h0), eh1 = exp2r(c2 * h1);
        float ei0 = exp2r(c2 * i0), ei1 = exp2r(c2 * i1);
        float ej0 = exp2r(c2 * j0), ej1 = exp2r(c2 * j1);
        float ek0 = exp2r(c2 * k0), ek1 = exp2r(c2 * k1);
        float el0 = exp2r(c2 * l0), el1 = exp2r(c2 * l1);
        D0 += ea0; S0 += a0 * ea0;
        D1 += ea1; S1 += a1 * ea1;
        D2 += eb0; S2 += b0 * eb0;
        D3 += eb1; S3 += b1 * eb1;
        D4 += eg0; S4 += g0 * eg0;
        D5 += eg1; S5 += g1 * eg1;
        D6 += eh0; S6 += h0 * eh0;
        D7 += eh1; S7 += h1 * eh1;
        D0 += ei0; S0 += i0 * ei0;
        D1 += ei1; S1 += i1 * ei1;
        D2 += ej0; S2 += j0 * ej0;
        D3 += ej1; S3 += j1 * ej1;
        D4 += ek0; S4 += k0 * ek0;
        D5 += ek1; S5 += k1 * ek1;
        D6 += el0; S6 += l0 * el0;
        D7 += el1; S7 += l1 * el1;
      }
      if (e + 3 < end) {
        unsigned o0 = ((unsigned)ssrc[e] << 7) + cl4;
        unsigned o1 = ((unsigned)ssrc[e + 1] << 7) + cl4;
        unsigned o2 = ((unsigned)ssrc[e + 2] << 7) + cl4;
        unsigned o3 = ((unsigned)ssrc[e + 3] << 7) + cl4;
        unsigned u0 = *(const unsigned*)(xbase + o0);
        unsigned u1 = *(const unsigned*)(xbase + o1);
        unsigned u2 = *(const unsigned*)(xbase + o2);
        unsigned u3 = *(const unsigned*)(xbase + o3);
        CH(u0, a0, a1) CH(u1, b0, b1) CH(u2, g0, g1) CH(u3, h0, h1)
        float ea0 = exp2r(c2 * a0), ea1 = exp2r(c2 * a1);
        float eb0 = exp2r(c2 * b0), eb1 = exp2r(c2 * b1);
        float eg0 = exp2r(c2 * g0), eg1 = exp2r(c2 * g1);
        float eh0 = exp2r(c2 * h0), eh1 = exp2r(c2 * h1);
        D0 += ea0; S0 += a0 * ea0;
        D1 += ea1; S1 += a1 * ea1;
        D2 += eb0; S2 += b0 * eb0;
        D3 += eb1; S3 += b1 * eb1;
        D4 += eg0; S4 += g0 * eg0;
        D5 += eg1; S5 += g1 * eg1;
        D6 += eh0; S6 += h0 * eh0;
        D7 += eh1; S7 += h1 * eh1;
        e += 4;
      }
      for (; e < end; ++e) {
        unsigned o0 = ((unsigned)ssrc[e] << 7) + cl4;
        unsigned u0 = *(const unsigned*)(xbase + o0);
        CH(u0, a0, a1)
        float ea0 = exp2r(c2 * a0), ea1 = exp2r(c2 * a1);
        D0 += ea0; S0 += a0 * ea0;
        D1 += ea1; S1 += a1 * ea1;
      }
#undef CH
      float Da = (D0 + D2) + (D4 + D6), Sa = (S0 + S2) + (S4 + S6);
      float Db = (D1 + D3) + (D5 + D7), Sb = (S1 + S3) + (S5 + S7);
      int has = (end > beg);
      float agg0 = has ? (Sa / Da + 1e-7f) : 0.f;
      float agg1 = has ? (Sb / Db + 1e-7f) : 0.f;
      float na = agg0 * agg0 + agg1 * agg1;
      float nx = xv0 * xv0 + xv1 * xv1;
#pragma unroll
      for (int m = 1; m < 32; m <<= 1) {
        na += __shfl_xor(na, m, 64);
        nx += __shfl_xor(nx, m, 64);
      }
      float inv = sc * sqrtf(nx) / fmaxf(sqrtf(na), 1e-12f);
      sxw[w][(2 * p + half) * 36 + cl] = pack2bf(xv0 + inv * agg0, xv1 + inv * agg1);
    }
  }

  // ---- phase M: MLP (R13-proven), A-frags from wave-private X-scratch ----
  bf16x8 xa0 = *(const bf16x8*)&sxw[w][fr * 36 + fq * 4];
  bf16x8 xa1 = *(const bf16x8*)&sxw[w][fr * 36 + 16 + fq * 4];
  f32x4 c1[8];
#pragma unroll
  for (int nt = 0; nt < 8; nt++) {
    f32x4 a = {0.f, 0.f, 0.f, 0.f};
    bf16x8 w0 = *(const bf16x8*)&W1p[(size_t)(nt * 16 + fr) * 36 + fq * 4];
    bf16x8 w1 = *(const bf16x8*)&W1p[(size_t)(nt * 16 + fr) * 36 + 16 + fq * 4];
    a = __builtin_amdgcn_mfma_f32_16x16x32_bf16(xa0, w0, a, 0, 0, 0);
    a = __builtin_amdgcn_mfma_f32_16x16x32_bf16(xa1, w1, a, 0, 0, 0);
    c1[nt] = a;
  }
  float b1v[8], g1v[8], bb1v[8];
#pragma unroll
  for (int nt = 0; nt < 8; nt++) {
    b1v[nt] = b1[nt * 16 + fr];
    g1v[nt] = g1[nt * 16 + fr];
    bb1v[nt] = bb1[nt * 16 + fr];
  }
#pragma unroll
  for (int r = 0; r < 4; r++) {
    float s1 = 0.f, s2 = 0.f;
#pragma unroll
    for (int nt = 0; nt < 8; nt++) {
      float u = c1[nt][r] + b1v[nt];
      s1 += u;
      s2 += u * u;
    }
#pragma unroll
    for (int m = 1; m < 16; m <<= 1) {
      s1 += __shfl_xor(s1, m, 64);
      s2 += __shfl_xor(s2, m, 64);
    }
    float mu = s1 * (1.f / 128.f);
    float var = s2 * (1.f / 128.f) - mu * mu;
    float rs = rsqrtf(var + 1e-5f);
    int row = fq * 4 + r;
#pragma unroll
    for (int nt = 0; nt < 8; nt++) {
      float u = c1[nt][r] + b1v[nt];
      u = fmaxf((u - mu) * rs * g1v[nt] + bb1v[nt], 0.f);
      scr[w][row][nt * 16 + fr] = (unsigned short)bf16rne(u);
    }
  }
  bf16x8 ua[4];
#pragma unroll
  for (int s = 0; s < 4; s++) ua[s] = *(const bf16x8*)&scr[w][fr][s * 32 + fq * 8];
  f32x4 c2[4];
#pragma unroll
  for (int nt = 0; nt < 4; nt++) {
    f32x4 a = {0.f, 0.f, 0.f, 0.f};
#pragma unroll
    for (int s = 0; s < 4; s++) {
      bf16x8 wf = *(const bf16x8*)&W2p[(size_t)(nt * 16 + fr) * 68 + s * 16 + fq * 4];
      a = __builtin_amdgcn_mfma_f32_16x16x32_bf16(ua[s], wf, a, 0, 0, 0);
    }
    c2[nt] = a;
  }
  float b2v[4], gv[4], bv[4];
#pragma unroll
  for (int nt = 0; nt < 4; nt++) {
    b2v[nt] = b2[nt * 16 + fr];
    gv[nt] = gn[nt * 16 + fr];
    bv[nt] = bn[nt * 16 + fr];
  }
#pragma unroll
  for (int r = 0; r < 4; r++) {
    int row = fq * 4 + r;
    size_t base = (size_t)(node0 + row) * DIM_H;
    float o0, o1, o2, o3, s1, s2;
    o0 = c2[0][r] + b2v[0];
    o1 = c2[1][r] + b2v[1];
    o2 = c2[2][r] + b2v[2];
    o3 = c2[3][r] + b2v[3];
    if (residual) {
      o0 += h[base + 0 * 16 + fr];
      o1 += h[base + 1 * 16 + fr];
      o2 += h[base + 2 * 16 + fr];
      o3 += h[base + 3 * 16 + fr];
    }
    s1 = (o0 + o1) + (o2 + o3);
    s2 = (o0 * o0 + o1 * o1) + (o2 * o2 + o3 * o3);
#pragma unroll
    for (int m = 1; m < 16; m <<= 1) {
      s1 += __shfl_xor(s1, m, 64);
      s2 += __shfl_xor(s2, m, 64);
    }
    float mu = s1 * (1.f / 64.f);
    float var = s2 * (1.f / 64.f) - mu * mu;
    float rs = rsqrtf(var + 1e-5f);
    h[base + 0 * 16 + fr] = o0;
    h[base + 1 * 16 + fr] = o1;
    h[base + 2 * 16 + fr] = o2;
    h[base + 3 * 16 + fr] = o3;
    rnext[base + 0 * 16 + fr] = (unsigned short)bf16rne(fmaxf((o0 - mu) * rs * gv[0] + bv[0], 0.f));
    rnext[base + 1 * 16 + fr] = (unsigned short)bf16rne(fmaxf((o1 - mu) * rs * gv[1] + bv[1], 0.f));
    rnext[base + 2 * 16 + fr] = (unsigned short)bf16rne(fmaxf((o2 - mu) * rs * gv[2] + bv[2], 0.f));
    rnext[base + 3 * 16 + fr] = (unsigned short)bf16rne(fmaxf((o3 - mu) * rs * gv[3] + bv[3], 0.f));
  }
}

// ---------------- final via MFMA: out = rB @ lin_W + lin_b ------------------
// R13-proven, unchanged.

__global__ __launch_bounds__(256, 2) void k_final(const unsigned* __restrict__ rB32,
                                                  const unsigned* __restrict__ Wp,
                                                  const float* __restrict__ bias,
                                                  float* __restrict__ out) {
  int t = threadIdx.x;
  int w = t >> 6, lane = t & 63;
  int wid = blockIdx.x * 4 + w;
  if (wid >= N_NODES / 16) return;
  int node0 = wid * 16;
  int fr = lane & 15, fq = lane >> 4;
  bf16x8 xa0 = *(const bf16x8*)&rB32[(size_t)(node0 + fr) * 32 + fq * 4];
  bf16x8 xa1 = *(const bf16x8*)&rB32[(size_t)(node0 + fr) * 32 + 16 + fq * 4];
#pragma unroll
  for (int nt = 0; nt < 7; nt++) {
    f32x4 a = {0.f, 0.f, 0.f, 0.f};
    bf16x8 w0 = *(const bf16x8*)&Wp[(size_t)(nt * 16 + fr) * 36 + fq * 4];
    bf16x8 w1 = *(const bf16x8*)&Wp[(size_t)(nt * 16 + fr) * 36 + 16 + fq * 4];
    a = __builtin_amdgcn_mfma_f32_16x16x32_bf16(xa0, w0, a, 0, 0, 0);
    a = __builtin_amdgcn_mfma_f32_16x16x32_bf16(xa1, w1, a, 0, 0, 0);
    float bv = bias[nt * 16 + fr];
#pragma unroll
    for (int r = 0; r < 4; r++)
      out[(size_t)(node0 + fq * 4 + r) * DIM_OUT + nt * 16 + fr] = a[r] + bv;
  }
}

// ---------------- launch ----------------

extern "C" void kernel_launch(void* const* d_in, const int* in_sizes, int n_in,
                              void* d_out, int out_size, void* d_ws, size_t ws_size,
                              hipStream_t stream) {
  const float* x = (const float*)d_in[0];
  const int* ei = (const int*)d_in[1];
  const float* encW = (const float*)d_in[2];
  const float* encb = (const float*)d_in[3];
  const float* t_arr = (const float*)d_in[4];
  const float* sc_arr = (const float*)d_in[5];
  const float* W1 = (const float*)d_in[6];
  const float* b1 = (const float*)d_in[7];
  const float* g1 = (const float*)d_in[8];
  const float* bb1 = (const float*)d_in[9];
  const float* W2 = (const float*)d_in[10];
  const float* b2 = (const float*)d_in[11];
  const float* ng = (const float*)d_in[12];
  const float* nbias = (const float*)d_in[13];
  const float* linW = (const float*)d_in[14];
  const float* linb = (const float*)d_in[15];

  float* hA = (float*)d_ws;                                             // N*64 f32 h-state
  unsigned short* rA = (unsigned short*)(hA + (size_t)N_NODES * DIM_H); // N*64 bf16 ping
  unsigned short* rB = rA + (size_t)N_NODES * DIM_H;                    // N*64 bf16 pong
  unsigned short* hBf = rB + (size_t)N_NODES * DIM_H;                   // N*64 bf16 enc-out
  int* ssrc = (int*)(hBf + (size_t)N_NODES * DIM_H);                    // E
  int* rank = ssrc + N_EDGES;                                           // E
  int* offs = rank + N_EDGES;                                           // N+1
  int* counts = offs + (N_NODES + 1);                                   // N
  int* bsums = counts + N_NODES;                                        // <=512
  unsigned* W1p = (unsigned*)(((uintptr_t)(bsums + 512) + 15) & ~(uintptr_t)15);
  unsigned* W2p = W1p + (size_t)N_LAYERS * W1P_SZ;
  unsigned* Wep = W2p + (size_t)N_LAYERS * W2P_SZ;
  unsigned* Wfp = Wep + WEP_SZ;

  const int* srcI = ei;
  const int* dstI = ei + N_EDGES;

  const int nbScan = (N_NODES + 255) / 256;   // 391
  const int nbEdge = (N_EDGES + 255) / 256;   // 4688
  const int nbWave = (N_NODES / 16 + 3) / 4;  // 1563 blocks of 4 waves

  // CSR build (rank-based) + weight pre-pack
  k_zero_i<<<nbScan, 256, 0, stream>>>(counts, N_NODES);
  k_hist<<<nbEdge, 256, 0, stream>>>(dstI, counts, rank);
  k_prepack<<<dim3(3, N_LAYERS), 256, 0, stream>>>(W1, W2, W1p, W2p);
  k_prepack_enc<<<3, 256, 0, stream>>>(encW, Wep);
  k_prepack_fin<<<3, 256, 0, stream>>>(linW, Wfp);
  k_scan1<<<nbScan, 256, 0, stream>>>(counts, bsums);
  k_scan2<<<1, 512, 0, stream>>>(bsums, nbScan);
  k_scan3<<<nbScan, 256, 0, stream>>>(counts, bsums, offs);
  k_scatter<<<nbEdge, 256, 0, stream>>>(srcI, dstI, rank, offs, ssrc);

  // encoder (MFMA) -> hBf (bf16)
  k_encoder<<<N_NODES / 32, 256, 0, stream>>>(x, Wep, encb, hBf);

  // layers 0..6: fused wave-autonomous edge+MLP; rIn/rOut ping-pong
  for (int i = 0; i < N_LAYERS; i++) {
    int nx = (i + 1 < N_LAYERS) ? (i + 1) : 0;
    const unsigned* rin = (const unsigned*)((i == 0) ? hBf : ((i & 1) ? rA : rB));
    unsigned short* rout = (i & 1) ? rB : rA;
    if (i == 0)
      k_layer<1><<<nbWave, 256, 0, stream>>>(
          rin, ssrc, offs, t_arr, sc_arr, i, hA, rout, W1p + (size_t)i * W1P_SZ,
          b1 + i * DIM_H2, g1 + i * DIM_H2, bb1 + i * DIM_H2, W2p + (size_t)i * W2P_SZ,
          b2 + i * DIM_H, ng + nx * DIM_H, nbias + nx * DIM_H, 0);
    else
      k_layer<0><<<nbWave, 256, 0, stream>>>(
          rin, ssrc, offs, t_arr, sc_arr, i, hA, rout, W1p + (size_t)i * W1P_SZ,
          b1 + i * DIM_H2, g1 + i * DIM_H2, bb1 + i * DIM_H2, W2p + (size_t)i * W2P_SZ,
          b2 + i * DIM_H, ng + nx * DIM_H, nbias + nx * DIM_H, 1);
  }

  // layer 6 wrote rout = rA = bf16(relu(LN(h, nrm_0))); MFMA GEMM -> out
  k_final<<<nbWave, 256, 0, stream>>>((const unsigned*)rA, Wfp, linb, (float*)d_out);
}

// Round 19
// 554.210 us; speedup vs baseline: 1.2423x; 1.2423x over previous
//
#include <hip/hip_runtime.h>

#define N_NODES 100000
#define N_EDGES 1200000
#define DIM_IN 128
#define DIM_H 64
#define DIM_H2 128
#define DIM_OUT 112
#define N_LAYERS 7

// pre-packed weight sizes (uints), padded strides baked in
#define W1P_SZ 4608  // 128 n * 36 kp-stride (kp<32 valid)
#define W2P_SZ 4352  // 64 n * 68 kp-stride (kp<64 valid)
#define WEP_SZ 4352  // encoder: 64 n * 68 kp-stride (kp<64 valid)
#define WFP_SZ 4032  // final: 112 n * 36 kp-stride (kp<32 valid)

typedef __attribute__((ext_vector_type(8))) short bf16x8;
typedef __attribute__((ext_vector_type(4))) float f32x4;
typedef __attribute__((ext_vector_type(2))) float f32x2;

// bf16 pack/unpack: bf16->f32 is just <<16 (bit ops, no cvt instruction)
__device__ __forceinline__ unsigned bf16rne(float f) {
  unsigned u = __float_as_uint(f);
  return (u + 0x7fffu + ((u >> 16) & 1u)) >> 16;
}
__device__ __forceinline__ unsigned pack2bf(float lo, float hi) {
  return bf16rne(lo) | (bf16rne(hi) << 16);
}
__device__ __forceinline__ float bflo(unsigned p) { return __uint_as_float(p << 16); }
__device__ __forceinline__ float bfhi(unsigned p) { return __uint_as_float(p & 0xffff0000u); }
// raw v_exp_f32 (2^x); __exp2f does not exist in HIP device code (R14 lesson)
__device__ __forceinline__ float exp2r(float x) { return __builtin_amdgcn_exp2f(x); }

// ---------------- preprocessing: CSR build (rank-based, R16-proven) ---------
// R17 lesson: returning atomicAdd costs ~32B/op at the coherence point;
// XCD-sharding changed nothing. Keep the simple single-array form.

__global__ void k_zero_i(int* __restrict__ p, int n) {
  int i = blockIdx.x * 256 + threadIdx.x;
  if (i < n) p[i] = 0;
}

__global__ void k_hist(const int* __restrict__ dst, int* __restrict__ counts,
                       int* __restrict__ rank) {
  int e = blockIdx.x * 256 + threadIdx.x;
  if (e < N_EDGES) rank[e] = atomicAdd(&counts[dst[e]], 1);
}

__global__ void k_scan1(const int* __restrict__ counts, int* __restrict__ bsums) {
  __shared__ int sd[256];
  int t = threadIdx.x;
  int i = blockIdx.x * 256 + t;
  sd[t] = (i < N_NODES) ? counts[i] : 0;
  __syncthreads();
  for (int s = 128; s > 0; s >>= 1) {
    if (t < s) sd[t] += sd[t + s];
    __syncthreads();
  }
  if (t == 0) bsums[blockIdx.x] = sd[0];
}

__global__ void k_scan2(int* __restrict__ bsums, int nb) {
  __shared__ int sd[512];
  int t = threadIdx.x;
  int v = (t < nb) ? bsums[t] : 0;
  sd[t] = v;
  __syncthreads();
  for (int o = 1; o < 512; o <<= 1) {
    int add = (t >= o) ? sd[t - o] : 0;
    __syncthreads();
    sd[t] += add;
    __syncthreads();
  }
  if (t < nb) bsums[t] = sd[t] - v;  // exclusive
}

__global__ void k_scan3(const int* __restrict__ counts, const int* __restrict__ bsums,
                        int* __restrict__ offs) {
  __shared__ int sd[256];
  int t = threadIdx.x;
  int i = blockIdx.x * 256 + t;
  int v = (i < N_NODES) ? counts[i] : 0;
  sd[t] = v;
  __syncthreads();
  for (int o = 1; o < 256; o <<= 1) {
    int add = (t >= o) ? sd[t - o] : 0;
    __syncthreads();
    sd[t] += add;
    __syncthreads();
  }
  int excl = sd[t] - v + bsums[blockIdx.x];
  if (i < N_NODES) offs[i] = excl;
  if (i == N_NODES - 1) offs[N_NODES] = excl + v;  // = E
}

// atomic-free scatter: position = offs[dst] + rank.
__global__ void k_scatter(const int* __restrict__ src, const int* __restrict__ dst,
                          const int* __restrict__ rank, const int* __restrict__ offs,
                          int* __restrict__ ssrc) {
  int e = blockIdx.x * 256 + threadIdx.x;
  if (e < N_EDGES) {
    int p = offs[dst[e]] + rank[e];
    ssrc[p] = src[e];
  }
}

// ---------------- weight pre-pack (once per launch) ----------------

__global__ void k_prepack(const float* __restrict__ W1, const float* __restrict__ W2,
                          unsigned* __restrict__ W1p, unsigned* __restrict__ W2p) {
  int L = blockIdx.y;
  const float* w1 = W1 + (size_t)L * DIM_H * DIM_H2;
  const float* w2 = W2 + (size_t)L * DIM_H2 * DIM_H;
  unsigned* o1 = W1p + (size_t)L * W1P_SZ;
  unsigned* o2 = W2p + (size_t)L * W2P_SZ;
  for (int i = blockIdx.x * 256 + threadIdx.x; i < W1P_SZ; i += gridDim.x * 256) {
    int n = i / 36, kp = i - n * 36;
    o1[i] = (kp < 32) ? pack2bf(w1[(size_t)(2 * kp) * DIM_H2 + n],
                                w1[(size_t)(2 * kp + 1) * DIM_H2 + n]) : 0u;
  }
  for (int i = blockIdx.x * 256 + threadIdx.x; i < W2P_SZ; i += gridDim.x * 256) {
    int n = i / 68, kp = i - n * 68;
    o2[i] = (kp < 64) ? pack2bf(w2[(size_t)(2 * kp) * DIM_H + n],
                                w2[(size_t)(2 * kp + 1) * DIM_H + n]) : 0u;
  }
}

__global__ void k_prepack_enc(const float* __restrict__ W, unsigned* __restrict__ Wp) {
  for (int i = blockIdx.x * 256 + threadIdx.x; i < WEP_SZ; i += gridDim.x * 256) {
    int n = i / 68, kp = i - n * 68;
    Wp[i] = (kp < 64) ? pack2bf(W[(size_t)(2 * kp) * DIM_H + n],
                                W[(size_t)(2 * kp + 1) * DIM_H + n]) : 0u;
  }
}

__global__ void k_prepack_fin(const float* __restrict__ W, unsigned* __restrict__ Wp) {
  for (int i = blockIdx.x * 256 + threadIdx.x; i < WFP_SZ; i += gridDim.x * 256) {
    int n = i / 36, kp = i - n * 36;
    Wp[i] = (kp < 32) ? pack2bf(W[(size_t)(2 * kp) * DIM_OUT + n],
                                W[(size_t)(2 * kp + 1) * DIM_OUT + n]) : 0u;
  }
}

// ---------------- encoder via MFMA: hBf = bf16(x @ enc_W + enc_b) ----------
// R12-proven, unchanged.

__global__ __launch_bounds__(256, 2) void k_encoder(const float* __restrict__ x,
                                                    const unsigned* __restrict__ Wp,
                                                    const float* __restrict__ bias,
                                                    unsigned short* __restrict__ hBf) {
  __shared__ __attribute__((aligned(16))) unsigned sW[WEP_SZ];    // 17.4KB [n<64][kp<64] s68
  __shared__ __attribute__((aligned(16))) unsigned sxp[32 * 68];  // 8.7KB [row][kp<64] s68
  int t = threadIdx.x;
  int node0 = blockIdx.x * 32;
  int w = t >> 6, lane = t & 63;
  int fr = lane & 15, fq = lane >> 4;
  const uint4* wv4 = (const uint4*)Wp;
  for (int i = t; i < WEP_SZ / 4; i += 256) *(uint4*)&sW[i * 4] = wv4[i];
  for (int i = t; i < 2048; i += 256) {  // 32 rows x 64 kp
    int row = i >> 6, kp = i & 63;
    float2 xv = *(const float2*)&x[(size_t)(node0 + row) * DIM_IN + 2 * kp];
    sxp[row * 68 + kp] = pack2bf(xv.x, xv.y);
  }
  __syncthreads();
  f32x4 acc0 = {0.f, 0.f, 0.f, 0.f}, acc1 = acc0;
#pragma unroll
  for (int s = 0; s < 4; s++) {
    int kp0 = s * 16 + fq * 4;
    bf16x8 a0 = *(const bf16x8*)&sxp[fr * 68 + kp0];
    bf16x8 a1 = *(const bf16x8*)&sxp[(16 + fr) * 68 + kp0];
    bf16x8 wf = *(const bf16x8*)&sW[(w * 16 + fr) * 68 + kp0];
    acc0 = __builtin_amdgcn_mfma_f32_16x16x32_bf16(a0, wf, acc0, 0, 0, 0);
    acc1 = __builtin_amdgcn_mfma_f32_16x16x32_bf16(a1, wf, acc1, 0, 0, 0);
  }
  float bv = bias[w * 16 + fr];
#pragma unroll
  for (int r = 0; r < 4; r++) {
    hBf[(size_t)(node0 + fq * 4 + r) * DIM_H + w * 16 + fr] =
        (unsigned short)bf16rne(acc0[r] + bv);
    hBf[(size_t)(node0 + 16 + fq * 4 + r) * DIM_H + w * 16 + fr] =
        (unsigned short)bf16rne(acc1[r] + bv);
  }
}

// ---------------- edge aggregation + MsgNorm (paired, f32x2 packed math) ----
// R17 split structure (gather at max occupancy — fusion proven worse twice).
// Per-uint channel-pair math in f32x2 so clang can form v_pk_mul/add/fma_f32
// (CDNA4 packed fp32); exp stays scalar on the trans pipe.

template <int RELU>
__global__ __launch_bounds__(256) void k_edge(const unsigned* __restrict__ xin32,
                                              const int* __restrict__ ssrc,
                                              const int* __restrict__ offs,
                                              const float* __restrict__ t_arr,
                                              const float* __restrict__ sc_arr, int layer,
                                              unsigned* __restrict__ hmid32) {
  int t = threadIdx.x;
  int wave = t >> 6, lane = t & 63;
  int half = lane >> 5, cl = lane & 31;
  int v = blockIdx.x * 8 + wave * 2 + half;
  float c2 = t_arr[layer] * 1.4426950408889634f;  // t * log2(e)
  f32x2 c2v = {c2, c2};
  float sc = sc_arr[layer];
  int beg = offs[v], end = offs[v + 1];
  unsigned cl4 = cl << 2;
  const char* xbase = (const char*)xin32;
  unsigned xp = *(const unsigned*)(xbase + (((unsigned)v << 7) + cl4));
  float xv0 = bflo(xp), xv1 = bfhi(xp);
  f32x2 Dv0 = {0.f, 0.f}, Dv1 = Dv0, Dv2 = Dv0, Dv3 = Dv0;
  f32x2 Sv0 = Dv0, Sv1 = Dv0, Sv2 = Dv0, Sv3 = Dv0;
  int e = beg;
#define UNPK(u, m)                                     \
  f32x2 m;                                             \
  m.x = RELU ? fmaxf(bflo(u), 0.f) : bflo(u);          \
  m.y = RELU ? fmaxf(bfhi(u), 0.f) : bfhi(u);
#define EXPV(m, ev)                                    \
  f32x2 ev;                                            \
  {                                                    \
    f32x2 z_ = c2v * m;                                \
    ev.x = exp2r(z_.x);                                \
    ev.y = exp2r(z_.y);                                \
  }
  for (; e + 7 < end; e += 8) {
    unsigned o0 = ((unsigned)ssrc[e] << 7) + cl4;
    unsigned o1 = ((unsigned)ssrc[e + 1] << 7) + cl4;
    unsigned o2 = ((unsigned)ssrc[e + 2] << 7) + cl4;
    unsigned o3 = ((unsigned)ssrc[e + 3] << 7) + cl4;
    unsigned o4 = ((unsigned)ssrc[e + 4] << 7) + cl4;
    unsigned o5 = ((unsigned)ssrc[e + 5] << 7) + cl4;
    unsigned o6 = ((unsigned)ssrc[e + 6] << 7) + cl4;
    unsigned o7 = ((unsigned)ssrc[e + 7] << 7) + cl4;
    unsigned u0 = *(const unsigned*)(xbase + o0);
    unsigned u1 = *(const unsigned*)(xbase + o1);
    unsigned u2 = *(const unsigned*)(xbase + o2);
    unsigned u3 = *(const unsigned*)(xbase + o3);
    unsigned u4 = *(const unsigned*)(xbase + o4);
    unsigned u5 = *(const unsigned*)(xbase + o5);
    unsigned u6 = *(const unsigned*)(xbase + o6);
    unsigned u7 = *(const unsigned*)(xbase + o7);
    UNPK(u0, m0) UNPK(u1, m1) UNPK(u2, m2) UNPK(u3, m3)
    UNPK(u4, m4) UNPK(u5, m5) UNPK(u6, m6) UNPK(u7, m7)
    EXPV(m0, e0) EXPV(m1, e1) EXPV(m2, e2) EXPV(m3, e3)
    EXPV(m4, e4) EXPV(m5, e5) EXPV(m6, e6) EXPV(m7, e7)
    Dv0 += e0; Sv0 += m0 * e0;
    Dv1 += e1; Sv1 += m1 * e1;
    Dv2 += e2; Sv2 += m2 * e2;
    Dv3 += e3; Sv3 += m3 * e3;
    Dv0 += e4; Sv0 += m4 * e4;
    Dv1 += e5; Sv1 += m5 * e5;
    Dv2 += e6; Sv2 += m6 * e6;
    Dv3 += e7; Sv3 += m7 * e7;
  }
  if (e + 3 < end) {
    unsigned o0 = ((unsigned)ssrc[e] << 7) + cl4;
    unsigned o1 = ((unsigned)ssrc[e + 1] << 7) + cl4;
    unsigned o2 = ((unsigned)ssrc[e + 2] << 7) + cl4;
    unsigned o3 = ((unsigned)ssrc[e + 3] << 7) + cl4;
    unsigned u0 = *(const unsigned*)(xbase + o0);
    unsigned u1 = *(const unsigned*)(xbase + o1);
    unsigned u2 = *(const unsigned*)(xbase + o2);
    unsigned u3 = *(const unsigned*)(xbase + o3);
    UNPK(u0, m0) UNPK(u1, m1) UNPK(u2, m2) UNPK(u3, m3)
    EXPV(m0, e0) EXPV(m1, e1) EXPV(m2, e2) EXPV(m3, e3)
    Dv0 += e0; Sv0 += m0 * e0;
    Dv1 += e1; Sv1 += m1 * e1;
    Dv2 += e2; Sv2 += m2 * e2;
    Dv3 += e3; Sv3 += m3 * e3;
    e += 4;
  }
  for (; e < end; ++e) {
    unsigned o0 = ((unsigned)ssrc[e] << 7) + cl4;
    unsigned u0 = *(const unsigned*)(xbase + o0);
    UNPK(u0, m0)
    EXPV(m0, e0)
    Dv0 += e0; Sv0 += m0 * e0;
  }
#undef UNPK
#undef EXPV
  f32x2 Dt = (Dv0 + Dv1) + (Dv2 + Dv3);
  f32x2 St = (Sv0 + Sv1) + (Sv2 + Sv3);
  int has = (end > beg);
  float agg0 = has ? (St.x / Dt.x + 1e-7f) : 0.f;
  float agg1 = has ? (St.y / Dt.y + 1e-7f) : 0.f;
  float na = agg0 * agg0 + agg1 * agg1;
  float nx = xv0 * xv0 + xv1 * xv1;
#pragma unroll
  for (int m = 1; m < 32; m <<= 1) {
    na += __shfl_xor(na, m, 64);
    nx += __shfl_xor(nx, m, 64);
  }
  float inv = sc * sqrtf(nx) / fmaxf(sqrtf(na), 1e-12f);
  float r0 = xv0 + inv * agg0;
  float r1 = xv1 + inv * agg1;
  hmid32[(size_t)v * 32 + cl] = pack2bf(r0, r1);
}

// ---------------- GENConv MLP: wave-autonomous, barrier-free MFMA ----------
// R13-proven, unchanged.

__global__ __launch_bounds__(256, 2) void k_mlp(const unsigned* __restrict__ xin32,
                                                float* __restrict__ h,
                                                unsigned short* __restrict__ rnext,
                                                const unsigned* __restrict__ W1p,
                                                const float* __restrict__ b1,
                                                const float* __restrict__ g1,
                                                const float* __restrict__ bb1,
                                                const unsigned* __restrict__ W2p,
                                                const float* __restrict__ b2,
                                                const float* __restrict__ gn,
                                                const float* __restrict__ bn, int residual) {
  __shared__ unsigned short scr[4][16][136];  // wave-private U scratch
  int t = threadIdx.x;
  int w = t >> 6, lane = t & 63;
  int wid = blockIdx.x * 4 + w;
  if (wid >= N_NODES / 16) return;  // 6250 waves exactly
  int node0 = wid * 16;
  int fr = lane & 15, fq = lane >> 4;

  // GEMM1: C1[16][128] = X[16][64] @ W1
  bf16x8 xa0 = *(const bf16x8*)&xin32[(size_t)(node0 + fr) * 32 + fq * 4];
  bf16x8 xa1 = *(const bf16x8*)&xin32[(size_t)(node0 + fr) * 32 + 16 + fq * 4];
  f32x4 c1[8];
#pragma unroll
  for (int nt = 0; nt < 8; nt++) {
    f32x4 a = {0.f, 0.f, 0.f, 0.f};
    bf16x8 w0 = *(const bf16x8*)&W1p[(size_t)(nt * 16 + fr) * 36 + fq * 4];
    bf16x8 w1 = *(const bf16x8*)&W1p[(size_t)(nt * 16 + fr) * 36 + 16 + fq * 4];
    a = __builtin_amdgcn_mfma_f32_16x16x32_bf16(xa0, w0, a, 0, 0, 0);
    a = __builtin_amdgcn_mfma_f32_16x16x32_bf16(xa1, w1, a, 0, 0, 0);
    c1[nt] = a;
  }
  // LN over 128 cols per row; lane holds C1[row=fq*4+r][col=nt*16+fr]
  float b1v[8], g1v[8], bb1v[8];
#pragma unroll
  for (int nt = 0; nt < 8; nt++) {
    b1v[nt] = b1[nt * 16 + fr];
    g1v[nt] = g1[nt * 16 + fr];
    bb1v[nt] = bb1[nt * 16 + fr];
  }
#pragma unroll
  for (int r = 0; r < 4; r++) {
    float s1 = 0.f, s2 = 0.f;
#pragma unroll
    for (int nt = 0; nt < 8; nt++) {
      float u = c1[nt][r] + b1v[nt];
      s1 += u;
      s2 += u * u;
    }
#pragma unroll
    for (int m = 1; m < 16; m <<= 1) {
      s1 += __shfl_xor(s1, m, 64);
      s2 += __shfl_xor(s2, m, 64);
    }
    float mu = s1 * (1.f / 128.f);
    float var = s2 * (1.f / 128.f) - mu * mu;
    float rs = rsqrtf(var + 1e-5f);
    int row = fq * 4 + r;
#pragma unroll
    for (int nt = 0; nt < 8; nt++) {
      float u = c1[nt][r] + b1v[nt];
      u = fmaxf((u - mu) * rs * g1v[nt] + bb1v[nt], 0.f);
      scr[w][row][nt * 16 + fr] = (unsigned short)bf16rne(u);
    }
  }
  // GEMM2: C2[16][64] = U[16][128] @ W2 (A-frag k = s*32+fq*8+e)
  bf16x8 ua[4];
#pragma unroll
  for (int s = 0; s < 4; s++) ua[s] = *(const bf16x8*)&scr[w][fr][s * 32 + fq * 8];
  f32x4 c2[4];
#pragma unroll
  for (int nt = 0; nt < 4; nt++) {
    f32x4 a = {0.f, 0.f, 0.f, 0.f};
#pragma unroll
    for (int s = 0; s < 4; s++) {
      bf16x8 wf = *(const bf16x8*)&W2p[(size_t)(nt * 16 + fr) * 68 + s * 16 + fq * 4];
      a = __builtin_amdgcn_mfma_f32_16x16x32_bf16(ua[s], wf, a, 0, 0, 0);
    }
    c2[nt] = a;
  }
  // epilogue: +b2 (+res) -> h f32; prenorm -> rnext bf16
  float b2v[4], gv[4], bv[4];
#pragma unroll
  for (int nt = 0; nt < 4; nt++) {
    b2v[nt] = b2[nt * 16 + fr];
    gv[nt] = gn[nt * 16 + fr];
    bv[nt] = bn[nt * 16 + fr];
  }
#pragma unroll
  for (int r = 0; r < 4; r++) {
    int row = fq * 4 + r;
    size_t base = (size_t)(node0 + row) * DIM_H;
    float o0, o1, o2, o3, s1, s2;
    o0 = c2[0][r] + b2v[0];
    o1 = c2[1][r] + b2v[1];
    o2 = c2[2][r] + b2v[2];
    o3 = c2[3][r] + b2v[3];
    if (residual) {
      o0 += h[base + 0 * 16 + fr];
      o1 += h[base + 1 * 16 + fr];
      o2 += h[base + 2 * 16 + fr];
      o3 += h[base + 3 * 16 + fr];
    }
    s1 = (o0 + o1) + (o2 + o3);
    s2 = (o0 * o0 + o1 * o1) + (o2 * o2 + o3 * o3);
#pragma unroll
    for (int m = 1; m < 16; m <<= 1) {
      s1 += __shfl_xor(s1, m, 64);
      s2 += __shfl_xor(s2, m, 64);
    }
    float mu = s1 * (1.f / 64.f);
    float var = s2 * (1.f / 64.f) - mu * mu;
    float rs = rsqrtf(var + 1e-5f);
    h[base + 0 * 16 + fr] = o0;
    h[base + 1 * 16 + fr] = o1;
    h[base + 2 * 16 + fr] = o2;
    h[base + 3 * 16 + fr] = o3;
    rnext[base + 0 * 16 + fr] = (unsigned short)bf16rne(fmaxf((o0 - mu) * rs * gv[0] + bv[0], 0.f));
    rnext[base + 1 * 16 + fr] = (unsigned short)bf16rne(fmaxf((o1 - mu) * rs * gv[1] + bv[1], 0.f));
    rnext[base + 2 * 16 + fr] = (unsigned short)bf16rne(fmaxf((o2 - mu) * rs * gv[2] + bv[2], 0.f));
    rnext[base + 3 * 16 + fr] = (unsigned short)bf16rne(fmaxf((o3 - mu) * rs * gv[3] + bv[3], 0.f));
  }
}

// ---------------- final via MFMA: out = rB @ lin_W + lin_b ------------------
// R13-proven, unchanged.

__global__ __launch_bounds__(256, 2) void k_final(const unsigned* __restrict__ rB32,
                                                  const unsigned* __restrict__ Wp,
                                                  const float* __restrict__ bias,
                                                  float* __restrict__ out) {
  int t = threadIdx.x;
  int w = t >> 6, lane = t & 63;
  int wid = blockIdx.x * 4 + w;
  if (wid >= N_NODES / 16) return;
  int node0 = wid * 16;
  int fr = lane & 15, fq = lane >> 4;
  bf16x8 xa0 = *(const bf16x8*)&rB32[(size_t)(node0 + fr) * 32 + fq * 4];
  bf16x8 xa1 = *(const bf16x8*)&rB32[(size_t)(node0 + fr) * 32 + 16 + fq * 4];
#pragma unroll
  for (int nt = 0; nt < 7; nt++) {
    f32x4 a = {0.f, 0.f, 0.f, 0.f};
    bf16x8 w0 = *(const bf16x8*)&Wp[(size_t)(nt * 16 + fr) * 36 + fq * 4];
    bf16x8 w1 = *(const bf16x8*)&Wp[(size_t)(nt * 16 + fr) * 36 + 16 + fq * 4];
    a = __builtin_amdgcn_mfma_f32_16x16x32_bf16(xa0, w0, a, 0, 0, 0);
    a = __builtin_amdgcn_mfma_f32_16x16x32_bf16(xa1, w1, a, 0, 0, 0);
    float bv = bias[nt * 16 + fr];
#pragma unroll
    for (int r = 0; r < 4; r++)
      out[(size_t)(node0 + fq * 4 + r) * DIM_OUT + nt * 16 + fr] = a[r] + bv;
  }
}

// ---------------- launch ----------------

extern "C" void kernel_launch(void* const* d_in, const int* in_sizes, int n_in,
                              void* d_out, int out_size, void* d_ws, size_t ws_size,
                              hipStream_t stream) {
  const float* x = (const float*)d_in[0];
  const int* ei = (const int*)d_in[1];
  const float* encW = (const float*)d_in[2];
  const float* encb = (const float*)d_in[3];
  const float* t_arr = (const float*)d_in[4];
  const float* sc_arr = (const float*)d_in[5];
  const float* W1 = (const float*)d_in[6];
  const float* b1 = (const float*)d_in[7];
  const float* g1 = (const float*)d_in[8];
  const float* bb1 = (const float*)d_in[9];
  const float* W2 = (const float*)d_in[10];
  const float* b2 = (const float*)d_in[11];
  const float* ng = (const float*)d_in[12];
  const float* nbias = (const float*)d_in[13];
  const float* linW = (const float*)d_in[14];
  const float* linb = (const float*)d_in[15];

  float* hA = (float*)d_ws;                                             // N*64 f32 h-state
  unsigned short* mCbf = (unsigned short*)(hA + (size_t)N_NODES * DIM_H);  // N*64 bf16 edge-out
  unsigned short* rBf = mCbf + (size_t)N_NODES * DIM_H;                 // N*64 bf16
  unsigned short* hBf = rBf + (size_t)N_NODES * DIM_H;                  // N*64 bf16
  int* ssrc = (int*)(hBf + (size_t)N_NODES * DIM_H);                    // E
  int* rank = ssrc + N_EDGES;                                           // E
  int* offs = rank + N_EDGES;                                           // N+1
  int* counts = offs + (N_NODES + 1);                                   // N
  int* bsums = counts + N_NODES;                                        // <=512
  unsigned* W1p = (unsigned*)(((uintptr_t)(bsums + 512) + 15) & ~(uintptr_t)15);
  unsigned* W2p = W1p + (size_t)N_LAYERS * W1P_SZ;
  unsigned* Wep = W2p + (size_t)N_LAYERS * W2P_SZ;
  unsigned* Wfp = Wep + WEP_SZ;

  const int* srcI = ei;
  const int* dstI = ei + N_EDGES;

  const int nbScan = (N_NODES + 255) / 256;   // 391
  const int nbEdge = (N_EDGES + 255) / 256;   // 4688
  const int nbWave = (N_NODES / 16 + 3) / 4;  // 1563 blocks of 4 waves

  // CSR build (rank-based) + weight pre-pack
  k_zero_i<<<nbScan, 256, 0, stream>>>(counts, N_NODES);
  k_hist<<<nbEdge, 256, 0, stream>>>(dstI, counts, rank);
  k_prepack<<<dim3(3, N_LAYERS), 256, 0, stream>>>(W1, W2, W1p, W2p);
  k_prepack_enc<<<3, 256, 0, stream>>>(encW, Wep);
  k_prepack_fin<<<3, 256, 0, stream>>>(linW, Wfp);
  k_scan1<<<nbScan, 256, 0, stream>>>(counts, bsums);
  k_scan2<<<1, 512, 0, stream>>>(bsums, nbScan);
  k_scan3<<<nbScan, 256, 0, stream>>>(counts, bsums, offs);
  k_scatter<<<nbEdge, 256, 0, stream>>>(srcI, dstI, rank, offs, ssrc);

  // encoder (MFMA) -> hBf (bf16)
  k_encoder<<<N_NODES / 32, 256, 0, stream>>>(x, Wep, encb, hBf);

  // layers 0..6: gather(paired bf16) -> mCbf -> wave-autonomous MFMA MLP
  for (int i = 0; i < N_LAYERS; i++) {
    int nx = (i + 1 < N_LAYERS) ? (i + 1) : 0;
    const unsigned* gin32 = (const unsigned*)((i == 0) ? hBf : rBf);
    if (i == 0)
      k_edge<1><<<N_NODES / 8, 256, 0, stream>>>(gin32, ssrc, offs, t_arr, sc_arr, i,
                                                 (unsigned*)mCbf);
    else
      k_edge<0><<<N_NODES / 8, 256, 0, stream>>>(gin32, ssrc, offs, t_arr, sc_arr, i,
                                                 (unsigned*)mCbf);
    k_mlp<<<nbWave, 256, 0, stream>>>(
        (const unsigned*)mCbf, hA, rBf, W1p + (size_t)i * W1P_SZ, b1 + i * DIM_H2,
        g1 + i * DIM_H2, bb1 + i * DIM_H2, W2p + (size_t)i * W2P_SZ, b2 + i * DIM_H,
        ng + nx * DIM_H, nbias + nx * DIM_H, (i > 0) ? 1 : 0);
  }

  // final: rBf = bf16(relu(LN(h, nrm_0))); MFMA GEMM straight to out
  k_final<<<nbWave, 256, 0, stream>>>((const unsigned*)rBf, Wfp, linb, (float*)d_out);
}

// Round 20
// 544.366 us; speedup vs baseline: 1.2648x; 1.0181x over previous
//
#include <hip/hip_runtime.h>

#define N_NODES 100000
#define N_EDGES 1200000
#define DIM_IN 128
#define DIM_H 64
#define DIM_H2 128
#define DIM_OUT 112
#define N_LAYERS 7

// pre-packed weight sizes (uints), padded strides baked in
#define W1P_SZ 4608  // 128 n * 36 kp-stride (kp<32 valid)
#define W2P_SZ 4352  // 64 n * 68 kp-stride (kp<64 valid)
#define WEP_SZ 4352  // encoder: 64 n * 68 kp-stride (kp<64 valid)
#define WFP_SZ 4032  // final: 112 n * 36 kp-stride (kp<32 valid)

typedef __attribute__((ext_vector_type(8))) short bf16x8;
typedef __attribute__((ext_vector_type(4))) float f32x4;
typedef __attribute__((ext_vector_type(2))) float f32x2;

// bf16 pack/unpack: bf16->f32 is just <<16 (bit ops, no cvt instruction)
__device__ __forceinline__ unsigned bf16rne(float f) {
  unsigned u = __float_as_uint(f);
  return (u + 0x7fffu + ((u >> 16) & 1u)) >> 16;
}
__device__ __forceinline__ unsigned pack2bf(float lo, float hi) {
  return bf16rne(lo) | (bf16rne(hi) << 16);
}
__device__ __forceinline__ float bflo(unsigned p) { return __uint_as_float(p << 16); }
__device__ __forceinline__ float bfhi(unsigned p) { return __uint_as_float(p & 0xffff0000u); }
// raw v_exp_f32 (2^x); __exp2f does not exist in HIP device code (R14 lesson)
__device__ __forceinline__ float exp2r(float x) { return __builtin_amdgcn_exp2f(x); }

// ---------------- preprocessing: CSR build (rank-based) ----------------
// R17 lesson: returning atomicAdd ~32B/op at coherence point; XCD-sharding
// useless. R20 experiment: pad counters to 1 line each (stride 16 ints) to
// cut per-line contention (~36 edges/line -> ~12).

__global__ void k_zero_i(int* __restrict__ p, int n) {
  int i = blockIdx.x * 256 + threadIdx.x;
  if (i < n) p[i] = 0;
}

__global__ void k_hist(const int* __restrict__ dst, int* __restrict__ counts16,
                       int* __restrict__ rank) {
  int e = blockIdx.x * 256 + threadIdx.x;
  if (e < N_EDGES) rank[e] = atomicAdd(&counts16[(size_t)dst[e] * 16], 1);
}

__global__ void k_scan1(const int* __restrict__ counts16, int* __restrict__ bsums) {
  __shared__ int sd[256];
  int t = threadIdx.x;
  int i = blockIdx.x * 256 + t;
  sd[t] = (i < N_NODES) ? counts16[(size_t)i * 16] : 0;
  __syncthreads();
  for (int s = 128; s > 0; s >>= 1) {
    if (t < s) sd[t] += sd[t + s];
    __syncthreads();
  }
  if (t == 0) bsums[blockIdx.x] = sd[0];
}

__global__ void k_scan2(int* __restrict__ bsums, int nb) {
  __shared__ int sd[512];
  int t = threadIdx.x;
  int v = (t < nb) ? bsums[t] : 0;
  sd[t] = v;
  __syncthreads();
  for (int o = 1; o < 512; o <<= 1) {
    int add = (t >= o) ? sd[t - o] : 0;
    __syncthreads();
    sd[t] += add;
    __syncthreads();
  }
  if (t < nb) bsums[t] = sd[t] - v;  // exclusive
}

__global__ void k_scan3(const int* __restrict__ counts16, const int* __restrict__ bsums,
                        int* __restrict__ offs) {
  __shared__ int sd[256];
  int t = threadIdx.x;
  int i = blockIdx.x * 256 + t;
  int v = (i < N_NODES) ? counts16[(size_t)i * 16] : 0;
  sd[t] = v;
  __syncthreads();
  for (int o = 1; o < 256; o <<= 1) {
    int add = (t >= o) ? sd[t - o] : 0;
    __syncthreads();
    sd[t] += add;
    __syncthreads();
  }
  int excl = sd[t] - v + bsums[blockIdx.x];
  if (i < N_NODES) offs[i] = excl;
  if (i == N_NODES - 1) offs[N_NODES] = excl + v;  // = E
}

// atomic-free scatter: position = offs[dst] + rank.
__global__ void k_scatter(const int* __restrict__ src, const int* __restrict__ dst,
                          const int* __restrict__ rank, const int* __restrict__ offs,
                          int* __restrict__ ssrc) {
  int e = blockIdx.x * 256 + threadIdx.x;
  if (e < N_EDGES) {
    int p = offs[dst[e]] + rank[e];
    ssrc[p] = src[e];
  }
}

// ---------------- degree-sorted node permutation (for k_edge pairing) -------
// Pair nodes of equal degree in one wave's two halves -> no loop divergence.

__global__ void k_dhist(const int* __restrict__ offs, int* __restrict__ dbuck) {
  __shared__ int lh[64];
  int t = threadIdx.x;
  int i = blockIdx.x * 256 + t;
  if (t < 64) lh[t] = 0;
  __syncthreads();
  if (i < N_NODES) {
    int deg = offs[i + 1] - offs[i];
    atomicAdd(&lh[min(deg, 63)], 1);
  }
  __syncthreads();
  if (t < 64 && lh[t]) atomicAdd(&dbuck[t], lh[t]);
}

__global__ void k_dscan(const int* __restrict__ dbuck, int* __restrict__ dcursor) {
  __shared__ int sd[64];
  int t = threadIdx.x;  // 1 block, 64 threads
  int v = dbuck[t];
  sd[t] = v;
  __syncthreads();
  for (int o = 1; o < 64; o <<= 1) {
    int add = (t >= o) ? sd[t - o] : 0;
    __syncthreads();
    sd[t] += add;
    __syncthreads();
  }
  dcursor[t] = sd[t] - v;  // exclusive
}

__global__ void k_dscatter(const int* __restrict__ offs, int* __restrict__ dcursor,
                           int* __restrict__ perm) {
  __shared__ int lh[64], lbase[64];
  int t = threadIdx.x;
  int i = blockIdx.x * 256 + t;
  if (t < 64) lh[t] = 0;
  __syncthreads();
  int b = 0, lr = 0;
  if (i < N_NODES) {
    int deg = offs[i + 1] - offs[i];
    b = min(deg, 63);
    lr = atomicAdd(&lh[b], 1);
  }
  __syncthreads();
  if (t < 64) lbase[t] = lh[t] ? atomicAdd(&dcursor[t], lh[t]) : 0;
  __syncthreads();
  if (i < N_NODES) perm[lbase[b] + lr] = i;
}

// ---------------- weight pre-pack (once per launch) ----------------

__global__ void k_prepack(const float* __restrict__ W1, const float* __restrict__ W2,
                          unsigned* __restrict__ W1p, unsigned* __restrict__ W2p) {
  int L = blockIdx.y;
  const float* w1 = W1 + (size_t)L * DIM_H * DIM_H2;
  const float* w2 = W2 + (size_t)L * DIM_H2 * DIM_H;
  unsigned* o1 = W1p + (size_t)L * W1P_SZ;
  unsigned* o2 = W2p + (size_t)L * W2P_SZ;
  for (int i = blockIdx.x * 256 + threadIdx.x; i < W1P_SZ; i += gridDim.x * 256) {
    int n = i / 36, kp = i - n * 36;
    o1[i] = (kp < 32) ? pack2bf(w1[(size_t)(2 * kp) * DIM_H2 + n],
                                w1[(size_t)(2 * kp + 1) * DIM_H2 + n]) : 0u;
  }
  for (int i = blockIdx.x * 256 + threadIdx.x; i < W2P_SZ; i += gridDim.x * 256) {
    int n = i / 68, kp = i - n * 68;
    o2[i] = (kp < 64) ? pack2bf(w2[(size_t)(2 * kp) * DIM_H + n],
                                w2[(size_t)(2 * kp + 1) * DIM_H + n]) : 0u;
  }
}

__global__ void k_prepack_enc(const float* __restrict__ W, unsigned* __restrict__ Wp) {
  for (int i = blockIdx.x * 256 + threadIdx.x; i < WEP_SZ; i += gridDim.x * 256) {
    int n = i / 68, kp = i - n * 68;
    Wp[i] = (kp < 64) ? pack2bf(W[(size_t)(2 * kp) * DIM_H + n],
                                W[(size_t)(2 * kp + 1) * DIM_H + n]) : 0u;
  }
}

__global__ void k_prepack_fin(const float* __restrict__ W, unsigned* __restrict__ Wp) {
  for (int i = blockIdx.x * 256 + threadIdx.x; i < WFP_SZ; i += gridDim.x * 256) {
    int n = i / 36, kp = i - n * 36;
    Wp[i] = (kp < 32) ? pack2bf(W[(size_t)(2 * kp) * DIM_OUT + n],
                                W[(size_t)(2 * kp + 1) * DIM_OUT + n]) : 0u;
  }
}

// ---------------- encoder via MFMA: hBf = bf16(x @ enc_W + enc_b) ----------
// R12-proven, unchanged.

__global__ __launch_bounds__(256, 2) void k_encoder(const float* __restrict__ x,
                                                    const unsigned* __restrict__ Wp,
                                                    const float* __restrict__ bias,
                                                    unsigned short* __restrict__ hBf) {
  __shared__ __attribute__((aligned(16))) unsigned sW[WEP_SZ];    // 17.4KB [n<64][kp<64] s68
  __shared__ __attribute__((aligned(16))) unsigned sxp[32 * 68];  // 8.7KB [row][kp<64] s68
  int t = threadIdx.x;
  int node0 = blockIdx.x * 32;
  int w = t >> 6, lane = t & 63;
  int fr = lane & 15, fq = lane >> 4;
  const uint4* wv4 = (const uint4*)Wp;
  for (int i = t; i < WEP_SZ / 4; i += 256) *(uint4*)&sW[i * 4] = wv4[i];
  for (int i = t; i < 2048; i += 256) {  // 32 rows x 64 kp
    int row = i >> 6, kp = i & 63;
    float2 xv = *(const float2*)&x[(size_t)(node0 + row) * DIM_IN + 2 * kp];
    sxp[row * 68 + kp] = pack2bf(xv.x, xv.y);
  }
  __syncthreads();
  f32x4 acc0 = {0.f, 0.f, 0.f, 0.f}, acc1 = acc0;
#pragma unroll
  for (int s = 0; s < 4; s++) {
    int kp0 = s * 16 + fq * 4;
    bf16x8 a0 = *(const bf16x8*)&sxp[fr * 68 + kp0];
    bf16x8 a1 = *(const bf16x8*)&sxp[(16 + fr) * 68 + kp0];
    bf16x8 wf = *(const bf16x8*)&sW[(w * 16 + fr) * 68 + kp0];
    acc0 = __builtin_amdgcn_mfma_f32_16x16x32_bf16(a0, wf, acc0, 0, 0, 0);
    acc1 = __builtin_amdgcn_mfma_f32_16x16x32_bf16(a1, wf, acc1, 0, 0, 0);
  }
  float bv = bias[w * 16 + fr];
#pragma unroll
  for (int r = 0; r < 4; r++) {
    hBf[(size_t)(node0 + fq * 4 + r) * DIM_H + w * 16 + fr] =
        (unsigned short)bf16rne(acc0[r] + bv);
    hBf[(size_t)(node0 + 16 + fq * 4 + r) * DIM_H + w * 16 + fr] =
        (unsigned short)bf16rne(acc1[r] + bv);
  }
}

// ---------------- edge aggregation + MsgNorm (paired, degree-matched) -------
// v = perm[gid]: both wave halves process equal-degree nodes -> no divergence.

template <int RELU>
__global__ __launch_bounds__(256) void k_edge(const unsigned* __restrict__ xin32,
                                              const int* __restrict__ ssrc,
                                              const int* __restrict__ offs,
                                              const int* __restrict__ perm,
                                              const float* __restrict__ t_arr,
                                              const float* __restrict__ sc_arr, int layer,
                                              unsigned* __restrict__ hmid32) {
  int t = threadIdx.x;
  int wave = t >> 6, lane = t & 63;
  int half = lane >> 5, cl = lane & 31;
  int gid = blockIdx.x * 8 + wave * 2 + half;
  int v = perm[gid];
  float c2 = t_arr[layer] * 1.4426950408889634f;  // t * log2(e)
  f32x2 c2v = {c2, c2};
  float sc = sc_arr[layer];
  int beg = offs[v], end = offs[v + 1];
  unsigned cl4 = cl << 2;
  const char* xbase = (const char*)xin32;
  unsigned xp = *(const unsigned*)(xbase + (((unsigned)v << 7) + cl4));
  float xv0 = bflo(xp), xv1 = bfhi(xp);
  f32x2 Dv0 = {0.f, 0.f}, Dv1 = Dv0, Dv2 = Dv0, Dv3 = Dv0;
  f32x2 Sv0 = Dv0, Sv1 = Dv0, Sv2 = Dv0, Sv3 = Dv0;
  int e = beg;
#define UNPK(u, m)                                     \
  f32x2 m;                                             \
  m.x = RELU ? fmaxf(bflo(u), 0.f) : bflo(u);          \
  m.y = RELU ? fmaxf(bfhi(u), 0.f) : bfhi(u);
#define EXPV(m, ev)                                    \
  f32x2 ev;                                            \
  {                                                    \
    f32x2 z_ = c2v * m;                                \
    ev.x = exp2r(z_.x);                                \
    ev.y = exp2r(z_.y);                                \
  }
  for (; e + 7 < end; e += 8) {
    unsigned o0 = ((unsigned)ssrc[e] << 7) + cl4;
    unsigned o1 = ((unsigned)ssrc[e + 1] << 7) + cl4;
    unsigned o2 = ((unsigned)ssrc[e + 2] << 7) + cl4;
    unsigned o3 = ((unsigned)ssrc[e + 3] << 7) + cl4;
    unsigned o4 = ((unsigned)ssrc[e + 4] << 7) + cl4;
    unsigned o5 = ((unsigned)ssrc[e + 5] << 7) + cl4;
    unsigned o6 = ((unsigned)ssrc[e + 6] << 7) + cl4;
    unsigned o7 = ((unsigned)ssrc[e + 7] << 7) + cl4;
    unsigned u0 = *(const unsigned*)(xbase + o0);
    unsigned u1 = *(const unsigned*)(xbase + o1);
    unsigned u2 = *(const unsigned*)(xbase + o2);
    unsigned u3 = *(const unsigned*)(xbase + o3);
    unsigned u4 = *(const unsigned*)(xbase + o4);
    unsigned u5 = *(const unsigned*)(xbase + o5);
    unsigned u6 = *(const unsigned*)(xbase + o6);
    unsigned u7 = *(const unsigned*)(xbase + o7);
    UNPK(u0, m0) UNPK(u1, m1) UNPK(u2, m2) UNPK(u3, m3)
    UNPK(u4, m4) UNPK(u5, m5) UNPK(u6, m6) UNPK(u7, m7)
    EXPV(m0, e0) EXPV(m1, e1) EXPV(m2, e2) EXPV(m3, e3)
    EXPV(m4, e4) EXPV(m5, e5) EXPV(m6, e6) EXPV(m7, e7)
    Dv0 += e0; Sv0 += m0 * e0;
    Dv1 += e1; Sv1 += m1 * e1;
    Dv2 += e2; Sv2 += m2 * e2;
    Dv3 += e3; Sv3 += m3 * e3;
    Dv0 += e4; Sv0 += m4 * e4;
    Dv1 += e5; Sv1 += m5 * e5;
    Dv2 += e6; Sv2 += m6 * e6;
    Dv3 += e7; Sv3 += m7 * e7;
  }
  if (e + 3 < end) {
    unsigned o0 = ((unsigned)ssrc[e] << 7) + cl4;
    unsigned o1 = ((unsigned)ssrc[e + 1] << 7) + cl4;
    unsigned o2 = ((unsigned)ssrc[e + 2] << 7) + cl4;
    unsigned o3 = ((unsigned)ssrc[e + 3] << 7) + cl4;
    unsigned u0 = *(const unsigned*)(xbase + o0);
    unsigned u1 = *(const unsigned*)(xbase + o1);
    unsigned u2 = *(const unsigned*)(xbase + o2);
    unsigned u3 = *(const unsigned*)(xbase + o3);
    UNPK(u0, m0) UNPK(u1, m1) UNPK(u2, m2) UNPK(u3, m3)
    EXPV(m0, e0) EXPV(m1, e1) EXPV(m2, e2) EXPV(m3, e3)
    Dv0 += e0; Sv0 += m0 * e0;
    Dv1 += e1; Sv1 += m1 * e1;
    Dv2 += e2; Sv2 += m2 * e2;
    Dv3 += e3; Sv3 += m3 * e3;
    e += 4;
  }
  for (; e < end; ++e) {
    unsigned o0 = ((unsigned)ssrc[e] << 7) + cl4;
    unsigned u0 = *(const unsigned*)(xbase + o0);
    UNPK(u0, m0)
    EXPV(m0, e0)
    Dv0 += e0; Sv0 += m0 * e0;
  }
#undef UNPK
#undef EXPV
  f32x2 Dt = (Dv0 + Dv1) + (Dv2 + Dv3);
  f32x2 St = (Sv0 + Sv1) + (Sv2 + Sv3);
  int has = (end > beg);
  float agg0 = has ? (St.x / Dt.x + 1e-7f) : 0.f;
  float agg1 = has ? (St.y / Dt.y + 1e-7f) : 0.f;
  float na = agg0 * agg0 + agg1 * agg1;
  float nx = xv0 * xv0 + xv1 * xv1;
#pragma unroll
  for (int m = 1; m < 32; m <<= 1) {
    na += __shfl_xor(na, m, 64);
    nx += __shfl_xor(nx, m, 64);
  }
  float inv = sc * sqrtf(nx) / fmaxf(sqrtf(na), 1e-12f);
  float r0 = xv0 + inv * agg0;
  float r1 = xv1 + inv * agg1;
  hmid32[(size_t)v * 32 + cl] = pack2bf(r0, r1);
}

// ---------------- GENConv MLP: wave-autonomous, barrier-free MFMA ----------
// R13-proven, unchanged.

__global__ __launch_bounds__(256, 2) void k_mlp(const unsigned* __restrict__ xin32,
                                                float* __restrict__ h,
                                                unsigned short* __restrict__ rnext,
                                                const unsigned* __restrict__ W1p,
                                                const float* __restrict__ b1,
                                                const float* __restrict__ g1,
                                                const float* __restrict__ bb1,
                                                const unsigned* __restrict__ W2p,
                                                const float* __restrict__ b2,
                                                const float* __restrict__ gn,
                                                const float* __restrict__ bn, int residual) {
  __shared__ unsigned short scr[4][16][136];  // wave-private U scratch
  int t = threadIdx.x;
  int w = t >> 6, lane = t & 63;
  int wid = blockIdx.x * 4 + w;
  if (wid >= N_NODES / 16) return;  // 6250 waves exactly
  int node0 = wid * 16;
  int fr = lane & 15, fq = lane >> 4;

  // GEMM1: C1[16][128] = X[16][64] @ W1
  bf16x8 xa0 = *(const bf16x8*)&xin32[(size_t)(node0 + fr) * 32 + fq * 4];
  bf16x8 xa1 = *(const bf16x8*)&xin32[(size_t)(node0 + fr) * 32 + 16 + fq * 4];
  f32x4 c1[8];
#pragma unroll
  for (int nt = 0; nt < 8; nt++) {
    f32x4 a = {0.f, 0.f, 0.f, 0.f};
    bf16x8 w0 = *(const bf16x8*)&W1p[(size_t)(nt * 16 + fr) * 36 + fq * 4];
    bf16x8 w1 = *(const bf16x8*)&W1p[(size_t)(nt * 16 + fr) * 36 + 16 + fq * 4];
    a = __builtin_amdgcn_mfma_f32_16x16x32_bf16(xa0, w0, a, 0, 0, 0);
    a = __builtin_amdgcn_mfma_f32_16x16x32_bf16(xa1, w1, a, 0, 0, 0);
    c1[nt] = a;
  }
  // LN over 128 cols per row; lane holds C1[row=fq*4+r][col=nt*16+fr]
  float b1v[8], g1v[8], bb1v[8];
#pragma unroll
  for (int nt = 0; nt < 8; nt++) {
    b1v[nt] = b1[nt * 16 + fr];
    g1v[nt] = g1[nt * 16 + fr];
    bb1v[nt] = bb1[nt * 16 + fr];
  }
#pragma unroll
  for (int r = 0; r < 4; r++) {
    float s1 = 0.f, s2 = 0.f;
#pragma unroll
    for (int nt = 0; nt < 8; nt++) {
      float u = c1[nt][r] + b1v[nt];
      s1 += u;
      s2 += u * u;
    }
#pragma unroll
    for (int m = 1; m < 16; m <<= 1) {
      s1 += __shfl_xor(s1, m, 64);
      s2 += __shfl_xor(s2, m, 64);
    }
    float mu = s1 * (1.f / 128.f);
    float var = s2 * (1.f / 128.f) - mu * mu;
    float rs = rsqrtf(var + 1e-5f);
    int row = fq * 4 + r;
#pragma unroll
    for (int nt = 0; nt < 8; nt++) {
      float u = c1[nt][r] + b1v[nt];
      u = fmaxf((u - mu) * rs * g1v[nt] + bb1v[nt], 0.f);
      scr[w][row][nt * 16 + fr] = (unsigned short)bf16rne(u);
    }
  }
  // GEMM2: C2[16][64] = U[16][128] @ W2 (A-frag k = s*32+fq*8+e)
  bf16x8 ua[4];
#pragma unroll
  for (int s = 0; s < 4; s++) ua[s] = *(const bf16x8*)&scr[w][fr][s * 32 + fq * 8];
  f32x4 c2[4];
#pragma unroll
  for (int nt = 0; nt < 4; nt++) {
    f32x4 a = {0.f, 0.f, 0.f, 0.f};
#pragma unroll
    for (int s = 0; s < 4; s++) {
      bf16x8 wf = *(const bf16x8*)&W2p[(size_t)(nt * 16 + fr) * 68 + s * 16 + fq * 4];
      a = __builtin_amdgcn_mfma_f32_16x16x32_bf16(ua[s], wf, a, 0, 0, 0);
    }
    c2[nt] = a;
  }
  // epilogue: +b2 (+res) -> h f32; prenorm -> rnext bf16
  float b2v[4], gv[4], bv[4];
#pragma unroll
  for (int nt = 0; nt < 4; nt++) {
    b2v[nt] = b2[nt * 16 + fr];
    gv[nt] = gn[nt * 16 + fr];
    bv[nt] = bn[nt * 16 + fr];
  }
#pragma unroll
  for (int r = 0; r < 4; r++) {
    int row = fq * 4 + r;
    size_t base = (size_t)(node0 + row) * DIM_H;
    float o0, o1, o2, o3, s1, s2;
    o0 = c2[0][r] + b2v[0];
    o1 = c2[1][r] + b2v[1];
    o2 = c2[2][r] + b2v[2];
    o3 = c2[3][r] + b2v[3];
    if (residual) {
      o0 += h[base + 0 * 16 + fr];
      o1 += h[base + 1 * 16 + fr];
      o2 += h[base + 2 * 16 + fr];
      o3 += h[base + 3 * 16 + fr];
    }
    s1 = (o0 + o1) + (o2 + o3);
    s2 = (o0 * o0 + o1 * o1) + (o2 * o2 + o3 * o3);
#pragma unroll
    for (int m = 1; m < 16; m <<= 1) {
      s1 += __shfl_xor(s1, m, 64);
      s2 += __shfl_xor(s2, m, 64);
    }
    float mu = s1 * (1.f / 64.f);
    float var = s2 * (1.f / 64.f) - mu * mu;
    float rs = rsqrtf(var + 1e-5f);
    h[base + 0 * 16 + fr] = o0;
    h[base + 1 * 16 + fr] = o1;
    h[base + 2 * 16 + fr] = o2;
    h[base + 3 * 16 + fr] = o3;
    rnext[base + 0 * 16 + fr] = (unsigned short)bf16rne(fmaxf((o0 - mu) * rs * gv[0] + bv[0], 0.f));
    rnext[base + 1 * 16 + fr] = (unsigned short)bf16rne(fmaxf((o1 - mu) * rs * gv[1] + bv[1], 0.f));
    rnext[base + 2 * 16 + fr] = (unsigned short)bf16rne(fmaxf((o2 - mu) * rs * gv[2] + bv[2], 0.f));
    rnext[base + 3 * 16 + fr] = (unsigned short)bf16rne(fmaxf((o3 - mu) * rs * gv[3] + bv[3], 0.f));
  }
}

// ---------------- final via MFMA: out = rB @ lin_W + lin_b ------------------
// R13-proven, unchanged.

__global__ __launch_bounds__(256, 2) void k_final(const unsigned* __restrict__ rB32,
                                                  const unsigned* __restrict__ Wp,
                                                  const float* __restrict__ bias,
                                                  float* __restrict__ out) {
  int t = threadIdx.x;
  int w = t >> 6, lane = t & 63;
  int wid = blockIdx.x * 4 + w;
  if (wid >= N_NODES / 16) return;
  int node0 = wid * 16;
  int fr = lane & 15, fq = lane >> 4;
  bf16x8 xa0 = *(const bf16x8*)&rB32[(size_t)(node0 + fr) * 32 + fq * 4];
  bf16x8 xa1 = *(const bf16x8*)&rB32[(size_t)(node0 + fr) * 32 + 16 + fq * 4];
#pragma unroll
  for (int nt = 0; nt < 7; nt++) {
    f32x4 a = {0.f, 0.f, 0.f, 0.f};
    bf16x8 w0 = *(const bf16x8*)&Wp[(size_t)(nt * 16 + fr) * 36 + fq * 4];
    bf16x8 w1 = *(const bf16x8*)&Wp[(size_t)(nt * 16 + fr) * 36 + 16 + fq * 4];
    a = __builtin_amdgcn_mfma_f32_16x16x32_bf16(xa0, w0, a, 0, 0, 0);
    a = __builtin_amdgcn_mfma_f32_16x16x32_bf16(xa1, w1, a, 0, 0, 0);
    float bv = bias[nt * 16 + fr];
#pragma unroll
    for (int r = 0; r < 4; r++)
      out[(size_t)(node0 + fq * 4 + r) * DIM_OUT + nt * 16 + fr] = a[r] + bv;
  }
}

// ---------------- launch ----------------

extern "C" void kernel_launch(void* const* d_in, const int* in_sizes, int n_in,
                              void* d_out, int out_size, void* d_ws, size_t ws_size,
                              hipStream_t stream) {
  const float* x = (const float*)d_in[0];
  const int* ei = (const int*)d_in[1];
  const float* encW = (const float*)d_in[2];
  const float* encb = (const float*)d_in[3];
  const float* t_arr = (const float*)d_in[4];
  const float* sc_arr = (const float*)d_in[5];
  const float* W1 = (const float*)d_in[6];
  const float* b1 = (const float*)d_in[7];
  const float* g1 = (const float*)d_in[8];
  const float* bb1 = (const float*)d_in[9];
  const float* W2 = (const float*)d_in[10];
  const float* b2 = (const float*)d_in[11];
  const float* ng = (const float*)d_in[12];
  const float* nbias = (const float*)d_in[13];
  const float* linW = (const float*)d_in[14];
  const float* linb = (const float*)d_in[15];

  float* hA = (float*)d_ws;                                             // N*64 f32 h-state
  unsigned short* mCbf = (unsigned short*)(hA + (size_t)N_NODES * DIM_H);  // N*64 bf16 edge-out
  unsigned short* rBf = mCbf + (size_t)N_NODES * DIM_H;                 // N*64 bf16
  unsigned short* hBf = rBf + (size_t)N_NODES * DIM_H;                  // N*64 bf16
  int* ssrc = (int*)(hBf + (size_t)N_NODES * DIM_H);                    // E
  int* rank = ssrc + N_EDGES;                                           // E
  int* offs = rank + N_EDGES;                                           // N+1
  int* perm = offs + (N_NODES + 1);                                     // N
  int* counts16 = perm + N_NODES;                                       // 16*N (padded)
  int* bsums = counts16 + (size_t)16 * N_NODES;                         // <=512
  int* dbuck = bsums + 512;                                             // 64
  int* dcursor = dbuck + 64;                                            // 64
  unsigned* W1p = (unsigned*)(((uintptr_t)(dcursor + 64) + 15) & ~(uintptr_t)15);
  unsigned* W2p = W1p + (size_t)N_LAYERS * W1P_SZ;
  unsigned* Wep = W2p + (size_t)N_LAYERS * W2P_SZ;
  unsigned* Wfp = Wep + WEP_SZ;

  const int* srcI = ei;
  const int* dstI = ei + N_EDGES;

  const int nbScan = (N_NODES + 255) / 256;   // 391
  const int nbEdge = (N_EDGES + 255) / 256;   // 4688
  const int nbWave = (N_NODES / 16 + 3) / 4;  // 1563 blocks of 4 waves

  // CSR build (rank-based, padded counters) + weight pre-pack
  k_zero_i<<<(16 * N_NODES + 255) / 256, 256, 0, stream>>>(counts16, 16 * N_NODES);
  k_zero_i<<<1, 256, 0, stream>>>(dbuck, 64);
  k_hist<<<nbEdge, 256, 0, stream>>>(dstI, counts16, rank);
  k_prepack<<<dim3(3, N_LAYERS), 256, 0, stream>>>(W1, W2, W1p, W2p);
  k_prepack_enc<<<3, 256, 0, stream>>>(encW, Wep);
  k_prepack_fin<<<3, 256, 0, stream>>>(linW, Wfp);
  k_scan1<<<nbScan, 256, 0, stream>>>(counts16, bsums);
  k_scan2<<<1, 512, 0, stream>>>(bsums, nbScan);
  k_scan3<<<nbScan, 256, 0, stream>>>(counts16, bsums, offs);
  k_scatter<<<nbEdge, 256, 0, stream>>>(srcI, dstI, rank, offs, ssrc);
  // degree-sorted perm (pair equal-degree nodes in k_edge)
  k_dhist<<<nbScan, 256, 0, stream>>>(offs, dbuck);
  k_dscan<<<1, 64, 0, stream>>>(dbuck, dcursor);
  k_dscatter<<<nbScan, 256, 0, stream>>>(offs, dcursor, perm);

  // encoder (MFMA) -> hBf (bf16)
  k_encoder<<<N_NODES / 32, 256, 0, stream>>>(x, Wep, encb, hBf);

  // layers 0..6: gather(paired bf16, degree-matched) -> mCbf -> MFMA MLP
  for (int i = 0; i < N_LAYERS; i++) {
    int nx = (i + 1 < N_LAYERS) ? (i + 1) : 0;
    const unsigned* gin32 = (const unsigned*)((i == 0) ? hBf : rBf);
    if (i == 0)
      k_edge<1><<<N_NODES / 8, 256, 0, stream>>>(gin32, ssrc, offs, perm, t_arr, sc_arr,
                                                 i, (unsigned*)mCbf);
    else
      k_edge<0><<<N_NODES / 8, 256, 0, stream>>>(gin32, ssrc, offs, perm, t_arr, sc_arr,
                                                 i, (unsigned*)mCbf);
    k_mlp<<<nbWave, 256, 0, stream>>>(
        (const unsigned*)mCbf, hA, rBf, W1p + (size_t)i * W1P_SZ, b1 + i * DIM_H2,
        g1 + i * DIM_H2, bb1 + i * DIM_H2, W2p + (size_t)i * W2P_SZ, b2 + i * DIM_H,
        ng + nx * DIM_H, nbias + nx * DIM_H, (i > 0) ? 1 : 0);
  }

  // final: rBf = bf16(relu(LN(h, nrm_0))); MFMA GEMM straight to out
  k_final<<<nbWave, 256, 0, stream>>>((const unsigned*)rBf, Wfp, linb, (float*)d_out);
}

// Round 21
// 523.187 us; speedup vs baseline: 1.3160x; 1.0405x over previous
//
#include <hip/hip_runtime.h>

#define N_NODES 100000
#define N_EDGES 1200000
#define DIM_IN 128
#define DIM_H 64
#define DIM_H2 128
#define DIM_OUT 112
#define N_LAYERS 7

// pre-packed weight sizes (uints), padded strides baked in
#define W1P_SZ 4608  // 128 n * 36 kp-stride (kp<32 valid)
#define W2P_SZ 4352  // 64 n * 68 kp-stride (kp<64 valid)
#define WEP_SZ 4352  // encoder: 64 n * 68 kp-stride (kp<64 valid)
#define WFP_SZ 4032  // final: 112 n * 36 kp-stride (kp<32 valid)

typedef __attribute__((ext_vector_type(8))) short bf16x8;
typedef __attribute__((ext_vector_type(4))) float f32x4;

// bf16 pack/unpack: bf16->f32 is just <<16 (bit ops, no cvt instruction)
__device__ __forceinline__ unsigned bf16rne(float f) {
  unsigned u = __float_as_uint(f);
  return (u + 0x7fffu + ((u >> 16) & 1u)) >> 16;
}
__device__ __forceinline__ unsigned pack2bf(float lo, float hi) {
  return bf16rne(lo) | (bf16rne(hi) << 16);
}
__device__ __forceinline__ float bflo(unsigned p) { return __uint_as_float(p << 16); }
__device__ __forceinline__ float bfhi(unsigned p) { return __uint_as_float(p & 0xffff0000u); }
// raw v_exp_f32 (2^x); __exp2f does not exist in HIP device code (R14 lesson)
__device__ __forceinline__ float exp2r(float x) { return __builtin_amdgcn_exp2f(x); }

// ---------------- preprocessing: CSR build (rank-based) ----------------
// R17/R20 lessons: returning atomicAdd ~35B/op memory-side regardless of
// sharding or line padding. ~49us is its floor short of a radix sort.

__global__ void k_zero_i(int* __restrict__ p, int n) {
  int i = blockIdx.x * 256 + threadIdx.x;
  if (i < n) p[i] = 0;
}

__global__ void k_hist(const int* __restrict__ dst, int* __restrict__ counts,
                       int* __restrict__ rank) {
  int e = blockIdx.x * 256 + threadIdx.x;
  if (e < N_EDGES) rank[e] = atomicAdd(&counts[dst[e]], 1);
}

__global__ void k_scan1(const int* __restrict__ counts, int* __restrict__ bsums) {
  __shared__ int sd[256];
  int t = threadIdx.x;
  int i = blockIdx.x * 256 + t;
  sd[t] = (i < N_NODES) ? counts[i] : 0;
  __syncthreads();
  for (int s = 128; s > 0; s >>= 1) {
    if (t < s) sd[t] += sd[t + s];
    __syncthreads();
  }
  if (t == 0) bsums[blockIdx.x] = sd[0];
}

__global__ void k_scan2(int* __restrict__ bsums, int nb) {
  __shared__ int sd[512];
  int t = threadIdx.x;
  int v = (t < nb) ? bsums[t] : 0;
  sd[t] = v;
  __syncthreads();
  for (int o = 1; o < 512; o <<= 1) {
    int add = (t >= o) ? sd[t - o] : 0;
    __syncthreads();
    sd[t] += add;
    __syncthreads();
  }
  if (t < nb) bsums[t] = sd[t] - v;  // exclusive
}

__global__ void k_scan3(const int* __restrict__ counts, const int* __restrict__ bsums,
                        int* __restrict__ offs) {
  __shared__ int sd[256];
  int t = threadIdx.x;
  int i = blockIdx.x * 256 + t;
  int v = (i < N_NODES) ? counts[i] : 0;
  sd[t] = v;
  __syncthreads();
  for (int o = 1; o < 256; o <<= 1) {
    int add = (t >= o) ? sd[t - o] : 0;
    __syncthreads();
    sd[t] += add;
    __syncthreads();
  }
  int excl = sd[t] - v + bsums[blockIdx.x];
  if (i < N_NODES) offs[i] = excl;
  if (i == N_NODES - 1) offs[N_NODES] = excl + v;  // = E
}

// atomic-free scatter: position = offs[dst] + rank.
__global__ void k_scatter(const int* __restrict__ src, const int* __restrict__ dst,
                          const int* __restrict__ rank, const int* __restrict__ offs,
                          int* __restrict__ ssrc) {
  int e = blockIdx.x * 256 + threadIdx.x;
  if (e < N_EDGES) {
    int p = offs[dst[e]] + rank[e];
    ssrc[p] = src[e];
  }
}

// ---------------- degree-sorted node permutation (R20-proven) ---------------
// Equal-degree nodes share a wave -> no pairing divergence in k_edge.

__global__ void k_dhist(const int* __restrict__ offs, int* __restrict__ dbuck) {
  __shared__ int lh[64];
  int t = threadIdx.x;
  int i = blockIdx.x * 256 + t;
  if (t < 64) lh[t] = 0;
  __syncthreads();
  if (i < N_NODES) {
    int deg = offs[i + 1] - offs[i];
    atomicAdd(&lh[min(deg, 63)], 1);
  }
  __syncthreads();
  if (t < 64 && lh[t]) atomicAdd(&dbuck[t], lh[t]);
}

__global__ void k_dscan(const int* __restrict__ dbuck, int* __restrict__ dcursor) {
  __shared__ int sd[64];
  int t = threadIdx.x;  // 1 block, 64 threads
  int v = dbuck[t];
  sd[t] = v;
  __syncthreads();
  for (int o = 1; o < 64; o <<= 1) {
    int add = (t >= o) ? sd[t - o] : 0;
    __syncthreads();
    sd[t] += add;
    __syncthreads();
  }
  dcursor[t] = sd[t] - v;  // exclusive
}

__global__ void k_dscatter(const int* __restrict__ offs, int* __restrict__ dcursor,
                           int* __restrict__ perm) {
  __shared__ int lh[64], lbase[64];
  int t = threadIdx.x;
  int i = blockIdx.x * 256 + t;
  if (t < 64) lh[t] = 0;
  __syncthreads();
  int b = 0, lr = 0;
  if (i < N_NODES) {
    int deg = offs[i + 1] - offs[i];
    b = min(deg, 63);
    lr = atomicAdd(&lh[b], 1);
  }
  __syncthreads();
  if (t < 64) lbase[t] = lh[t] ? atomicAdd(&dcursor[t], lh[t]) : 0;
  __syncthreads();
  if (i < N_NODES) perm[lbase[b] + lr] = i;
}

// ---------------- weight pre-pack (once per launch) ----------------

__global__ void k_prepack(const float* __restrict__ W1, const float* __restrict__ W2,
                          unsigned* __restrict__ W1p, unsigned* __restrict__ W2p) {
  int L = blockIdx.y;
  const float* w1 = W1 + (size_t)L * DIM_H * DIM_H2;
  const float* w2 = W2 + (size_t)L * DIM_H2 * DIM_H;
  unsigned* o1 = W1p + (size_t)L * W1P_SZ;
  unsigned* o2 = W2p + (size_t)L * W2P_SZ;
  for (int i = blockIdx.x * 256 + threadIdx.x; i < W1P_SZ; i += gridDim.x * 256) {
    int n = i / 36, kp = i - n * 36;
    o1[i] = (kp < 32) ? pack2bf(w1[(size_t)(2 * kp) * DIM_H2 + n],
                                w1[(size_t)(2 * kp + 1) * DIM_H2 + n]) : 0u;
  }
  for (int i = blockIdx.x * 256 + threadIdx.x; i < W2P_SZ; i += gridDim.x * 256) {
    int n = i / 68, kp = i - n * 68;
    o2[i] = (kp < 64) ? pack2bf(w2[(size_t)(2 * kp) * DIM_H + n],
                                w2[(size_t)(2 * kp + 1) * DIM_H + n]) : 0u;
  }
}

__global__ void k_prepack_enc(const float* __restrict__ W, unsigned* __restrict__ Wp) {
  for (int i = blockIdx.x * 256 + threadIdx.x; i < WEP_SZ; i += gridDim.x * 256) {
    int n = i / 68, kp = i - n * 68;
    Wp[i] = (kp < 64) ? pack2bf(W[(size_t)(2 * kp) * DIM_H + n],
                                W[(size_t)(2 * kp + 1) * DIM_H + n]) : 0u;
  }
}

__global__ void k_prepack_fin(const float* __restrict__ W, unsigned* __restrict__ Wp) {
  for (int i = blockIdx.x * 256 + threadIdx.x; i < WFP_SZ; i += gridDim.x * 256) {
    int n = i / 36, kp = i - n * 36;
    Wp[i] = (kp < 32) ? pack2bf(W[(size_t)(2 * kp) * DIM_OUT + n],
                                W[(size_t)(2 * kp + 1) * DIM_OUT + n]) : 0u;
  }
}

// ---------------- encoder via MFMA: hBf = bf16(x @ enc_W + enc_b) ----------
// R12-proven, unchanged.

__global__ __launch_bounds__(256, 2) void k_encoder(const float* __restrict__ x,
                                                    const unsigned* __restrict__ Wp,
                                                    const float* __restrict__ bias,
                                                    unsigned short* __restrict__ hBf) {
  __shared__ __attribute__((aligned(16))) unsigned sW[WEP_SZ];    // 17.4KB [n<64][kp<64] s68
  __shared__ __attribute__((aligned(16))) unsigned sxp[32 * 68];  // 8.7KB [row][kp<64] s68
  int t = threadIdx.x;
  int node0 = blockIdx.x * 32;
  int w = t >> 6, lane = t & 63;
  int fr = lane & 15, fq = lane >> 4;
  const uint4* wv4 = (const uint4*)Wp;
  for (int i = t; i < WEP_SZ / 4; i += 256) *(uint4*)&sW[i * 4] = wv4[i];
  for (int i = t; i < 2048; i += 256) {  // 32 rows x 64 kp
    int row = i >> 6, kp = i & 63;
    float2 xv = *(const float2*)&x[(size_t)(node0 + row) * DIM_IN + 2 * kp];
    sxp[row * 68 + kp] = pack2bf(xv.x, xv.y);
  }
  __syncthreads();
  f32x4 acc0 = {0.f, 0.f, 0.f, 0.f}, acc1 = acc0;
#pragma unroll
  for (int s = 0; s < 4; s++) {
    int kp0 = s * 16 + fq * 4;
    bf16x8 a0 = *(const bf16x8*)&sxp[fr * 68 + kp0];
    bf16x8 a1 = *(const bf16x8*)&sxp[(16 + fr) * 68 + kp0];
    bf16x8 wf = *(const bf16x8*)&sW[(w * 16 + fr) * 68 + kp0];
    acc0 = __builtin_amdgcn_mfma_f32_16x16x32_bf16(a0, wf, acc0, 0, 0, 0);
    acc1 = __builtin_amdgcn_mfma_f32_16x16x32_bf16(a1, wf, acc1, 0, 0, 0);
  }
  float bv = bias[w * 16 + fr];
#pragma unroll
  for (int r = 0; r < 4; r++) {
    hBf[(size_t)(node0 + fq * 4 + r) * DIM_H + w * 16 + fr] =
        (unsigned short)bf16rne(acc0[r] + bv);
    hBf[(size_t)(node0 + 16 + fq * 4 + r) * DIM_H + w * 16 + fr] =
        (unsigned short)bf16rne(acc1[r] + bv);
  }
}

// ---------------- edge aggregation + MsgNorm (uint2, 4 nodes/wave) ----------
// Quarter-wave (16 lanes) per node, lane covers channels {4cl..4cl+3} via one
// uint2 load. Per wave-load: 4 gathered rows (was 2) -> half the load/ssrc/
// addr instructions per edge. Degree-sorted perm makes quartets uniform.

template <int RELU>
__global__ __launch_bounds__(256) void k_edge(const unsigned* __restrict__ xin32,
                                              const int* __restrict__ ssrc,
                                              const int* __restrict__ offs,
                                              const int* __restrict__ perm,
                                              const float* __restrict__ t_arr,
                                              const float* __restrict__ sc_arr, int layer,
                                              uint2* __restrict__ hmid2) {
  int t = threadIdx.x;
  int wave = t >> 6, lane = t & 63;
  int q = lane >> 4, cl = lane & 15;
  int gid = blockIdx.x * 16 + wave * 4 + q;
  int v = perm[gid];
  float c2 = t_arr[layer] * 1.4426950408889634f;  // t * log2(e)
  float sc = sc_arr[layer];
  int beg = offs[v], end = offs[v + 1];
  unsigned cl8 = cl << 3;
  const char* xbase = (const char*)xin32;
  uint2 xp = *(const uint2*)(xbase + (((unsigned)v << 7) + cl8));
  f32x4 xv = {bflo(xp.x), bfhi(xp.x), bflo(xp.y), bfhi(xp.y)};
  f32x4 Dv0 = {0.f, 0.f, 0.f, 0.f}, Dv1 = Dv0, Dv2 = Dv0, Dv3 = Dv0;
  f32x4 Sv0 = Dv0, Sv1 = Dv0, Sv2 = Dv0, Sv3 = Dv0;
  int e = beg;
#define UNPK4(u, m)                                      \
  f32x4 m;                                               \
  m.x = RELU ? fmaxf(bflo(u.x), 0.f) : bflo(u.x);        \
  m.y = RELU ? fmaxf(bfhi(u.x), 0.f) : bfhi(u.x);        \
  m.z = RELU ? fmaxf(bflo(u.y), 0.f) : bflo(u.y);        \
  m.w = RELU ? fmaxf(bfhi(u.y), 0.f) : bfhi(u.y);
#define EXPV4(m, ev)                                     \
  f32x4 ev;                                              \
  ev.x = exp2r(c2 * m.x);                                \
  ev.y = exp2r(c2 * m.y);                                \
  ev.z = exp2r(c2 * m.z);                                \
  ev.w = exp2r(c2 * m.w);
  for (; e + 7 < end; e += 8) {
    unsigned o0 = ((unsigned)ssrc[e] << 7) + cl8;
    unsigned o1 = ((unsigned)ssrc[e + 1] << 7) + cl8;
    unsigned o2 = ((unsigned)ssrc[e + 2] << 7) + cl8;
    unsigned o3 = ((unsigned)ssrc[e + 3] << 7) + cl8;
    unsigned o4 = ((unsigned)ssrc[e + 4] << 7) + cl8;
    unsigned o5 = ((unsigned)ssrc[e + 5] << 7) + cl8;
    unsigned o6 = ((unsigned)ssrc[e + 6] << 7) + cl8;
    unsigned o7 = ((unsigned)ssrc[e + 7] << 7) + cl8;
    uint2 u0 = *(const uint2*)(xbase + o0);
    uint2 u1 = *(const uint2*)(xbase + o1);
    uint2 u2 = *(const uint2*)(xbase + o2);
    uint2 u3 = *(const uint2*)(xbase + o3);
    uint2 u4 = *(const uint2*)(xbase + o4);
    uint2 u5 = *(const uint2*)(xbase + o5);
    uint2 u6 = *(const uint2*)(xbase + o6);
    uint2 u7 = *(const uint2*)(xbase + o7);
    UNPK4(u0, m0) UNPK4(u1, m1) UNPK4(u2, m2) UNPK4(u3, m3)
    UNPK4(u4, m4) UNPK4(u5, m5) UNPK4(u6, m6) UNPK4(u7, m7)
    EXPV4(m0, e0) EXPV4(m1, e1) EXPV4(m2, e2) EXPV4(m3, e3)
    EXPV4(m4, e4) EXPV4(m5, e5) EXPV4(m6, e6) EXPV4(m7, e7)
    Dv0 += e0; Sv0 += m0 * e0;
    Dv1 += e1; Sv1 += m1 * e1;
    Dv2 += e2; Sv2 += m2 * e2;
    Dv3 += e3; Sv3 += m3 * e3;
    Dv0 += e4; Sv0 += m4 * e4;
    Dv1 += e5; Sv1 += m5 * e5;
    Dv2 += e6; Sv2 += m6 * e6;
    Dv3 += e7; Sv3 += m7 * e7;
  }
  if (e + 3 < end) {
    unsigned o0 = ((unsigned)ssrc[e] << 7) + cl8;
    unsigned o1 = ((unsigned)ssrc[e + 1] << 7) + cl8;
    unsigned o2 = ((unsigned)ssrc[e + 2] << 7) + cl8;
    unsigned o3 = ((unsigned)ssrc[e + 3] << 7) + cl8;
    uint2 u0 = *(const uint2*)(xbase + o0);
    uint2 u1 = *(const uint2*)(xbase + o1);
    uint2 u2 = *(const uint2*)(xbase + o2);
    uint2 u3 = *(const uint2*)(xbase + o3);
    UNPK4(u0, m0) UNPK4(u1, m1) UNPK4(u2, m2) UNPK4(u3, m3)
    EXPV4(m0, e0) EXPV4(m1, e1) EXPV4(m2, e2) EXPV4(m3, e3)
    Dv0 += e0; Sv0 += m0 * e0;
    Dv1 += e1; Sv1 += m1 * e1;
    Dv2 += e2; Sv2 += m2 * e2;
    Dv3 += e3; Sv3 += m3 * e3;
    e += 4;
  }
  for (; e < end; ++e) {
    unsigned o0 = ((unsigned)ssrc[e] << 7) + cl8;
    uint2 u0 = *(const uint2*)(xbase + o0);
    UNPK4(u0, m0)
    EXPV4(m0, e0)
    Dv0 += e0; Sv0 += m0 * e0;
  }
#undef UNPK4
#undef EXPV4
  f32x4 Dt = (Dv0 + Dv1) + (Dv2 + Dv3);
  f32x4 St = (Sv0 + Sv1) + (Sv2 + Sv3);
  int has = (end > beg);
  f32x4 agg;
  agg.x = has ? (St.x / Dt.x + 1e-7f) : 0.f;
  agg.y = has ? (St.y / Dt.y + 1e-7f) : 0.f;
  agg.z = has ? (St.z / Dt.z + 1e-7f) : 0.f;
  agg.w = has ? (St.w / Dt.w + 1e-7f) : 0.f;
  float na = (agg.x * agg.x + agg.y * agg.y) + (agg.z * agg.z + agg.w * agg.w);
  float nx = (xv.x * xv.x + xv.y * xv.y) + (xv.z * xv.z + xv.w * xv.w);
#pragma unroll
  for (int m = 1; m < 16; m <<= 1) {
    na += __shfl_xor(na, m, 64);
    nx += __shfl_xor(nx, m, 64);
  }
  float inv = sc * sqrtf(nx) / fmaxf(sqrtf(na), 1e-12f);
  uint2 outp;
  outp.x = pack2bf(xv.x + inv * agg.x, xv.y + inv * agg.y);
  outp.y = pack2bf(xv.z + inv * agg.z, xv.w + inv * agg.w);
  hmid2[(size_t)v * 16 + cl] = outp;
}

// ---------------- GENConv MLP: wave-autonomous, barrier-free MFMA ----------
// R13-proven. LAST=1 (layer 6): h is dead after -> skip the 25.6MB h store.

template <int LAST>
__global__ __launch_bounds__(256, 2) void k_mlp(const unsigned* __restrict__ xin32,
                                                float* __restrict__ h,
                                                unsigned short* __restrict__ rnext,
                                                const unsigned* __restrict__ W1p,
                                                const float* __restrict__ b1,
                                                const float* __restrict__ g1,
                                                const float* __restrict__ bb1,
                                                const unsigned* __restrict__ W2p,
                                                const float* __restrict__ b2,
                                                const float* __restrict__ gn,
                                                const float* __restrict__ bn, int residual) {
  __shared__ unsigned short scr[4][16][136];  // wave-private U scratch
  int t = threadIdx.x;
  int w = t >> 6, lane = t & 63;
  int wid = blockIdx.x * 4 + w;
  if (wid >= N_NODES / 16) return;  // 6250 waves exactly
  int node0 = wid * 16;
  int fr = lane & 15, fq = lane >> 4;

  // GEMM1: C1[16][128] = X[16][64] @ W1
  bf16x8 xa0 = *(const bf16x8*)&xin32[(size_t)(node0 + fr) * 32 + fq * 4];
  bf16x8 xa1 = *(const bf16x8*)&xin32[(size_t)(node0 + fr) * 32 + 16 + fq * 4];
  f32x4 c1[8];
#pragma unroll
  for (int nt = 0; nt < 8; nt++) {
    f32x4 a = {0.f, 0.f, 0.f, 0.f};
    bf16x8 w0 = *(const bf16x8*)&W1p[(size_t)(nt * 16 + fr) * 36 + fq * 4];
    bf16x8 w1 = *(const bf16x8*)&W1p[(size_t)(nt * 16 + fr) * 36 + 16 + fq * 4];
    a = __builtin_amdgcn_mfma_f32_16x16x32_bf16(xa0, w0, a, 0, 0, 0);
    a = __builtin_amdgcn_mfma_f32_16x16x32_bf16(xa1, w1, a, 0, 0, 0);
    c1[nt] = a;
  }
  // LN over 128 cols per row; lane holds C1[row=fq*4+r][col=nt*16+fr]
  float b1v[8], g1v[8], bb1v[8];
#pragma unroll
  for (int nt = 0; nt < 8; nt++) {
    b1v[nt] = b1[nt * 16 + fr];
    g1v[nt] = g1[nt * 16 + fr];
    bb1v[nt] = bb1[nt * 16 + fr];
  }
#pragma unroll
  for (int r = 0; r < 4; r++) {
    float s1 = 0.f, s2 = 0.f;
#pragma unroll
    for (int nt = 0; nt < 8; nt++) {
      float u = c1[nt][r] + b1v[nt];
      s1 += u;
      s2 += u * u;
    }
#pragma unroll
    for (int m = 1; m < 16; m <<= 1) {
      s1 += __shfl_xor(s1, m, 64);
      s2 += __shfl_xor(s2, m, 64);
    }
    float mu = s1 * (1.f / 128.f);
    float var = s2 * (1.f / 128.f) - mu * mu;
    float rs = rsqrtf(var + 1e-5f);
    int row = fq * 4 + r;
#pragma unroll
    for (int nt = 0; nt < 8; nt++) {
      float u = c1[nt][r] + b1v[nt];
      u = fmaxf((u - mu) * rs * g1v[nt] + bb1v[nt], 0.f);
      scr[w][row][nt * 16 + fr] = (unsigned short)bf16rne(u);
    }
  }
  // GEMM2: C2[16][64] = U[16][128] @ W2 (A-frag k = s*32+fq*8+e)
  bf16x8 ua[4];
#pragma unroll
  for (int s = 0; s < 4; s++) ua[s] = *(const bf16x8*)&scr[w][fr][s * 32 + fq * 8];
  f32x4 c2[4];
#pragma unroll
  for (int nt = 0; nt < 4; nt++) {
    f32x4 a = {0.f, 0.f, 0.f, 0.f};
#pragma unroll
    for (int s = 0; s < 4; s++) {
      bf16x8 wf = *(const bf16x8*)&W2p[(size_t)(nt * 16 + fr) * 68 + s * 16 + fq * 4];
      a = __builtin_amdgcn_mfma_f32_16x16x32_bf16(ua[s], wf, a, 0, 0, 0);
    }
    c2[nt] = a;
  }
  // epilogue: +b2 (+res) -> h f32 (skipped on LAST); prenorm -> rnext bf16
  float b2v[4], gv[4], bv[4];
#pragma unroll
  for (int nt = 0; nt < 4; nt++) {
    b2v[nt] = b2[nt * 16 + fr];
    gv[nt] = gn[nt * 16 + fr];
    bv[nt] = bn[nt * 16 + fr];
  }
#pragma unroll
  for (int r = 0; r < 4; r++) {
    int row = fq * 4 + r;
    size_t base = (size_t)(node0 + row) * DIM_H;
    float o0, o1, o2, o3, s1, s2;
    o0 = c2[0][r] + b2v[0];
    o1 = c2[1][r] + b2v[1];
    o2 = c2[2][r] + b2v[2];
    o3 = c2[3][r] + b2v[3];
    if (residual) {
      o0 += h[base + 0 * 16 + fr];
      o1 += h[base + 1 * 16 + fr];
      o2 += h[base + 2 * 16 + fr];
      o3 += h[base + 3 * 16 + fr];
    }
    s1 = (o0 + o1) + (o2 + o3);
    s2 = (o0 * o0 + o1 * o1) + (o2 * o2 + o3 * o3);
#pragma unroll
    for (int m = 1; m < 16; m <<= 1) {
      s1 += __shfl_xor(s1, m, 64);
      s2 += __shfl_xor(s2, m, 64);
    }
    float mu = s1 * (1.f / 64.f);
    float var = s2 * (1.f / 64.f) - mu * mu;
    float rs = rsqrtf(var + 1e-5f);
    if (!LAST) {
      h[base + 0 * 16 + fr] = o0;
      h[base + 1 * 16 + fr] = o1;
      h[base + 2 * 16 + fr] = o2;
      h[base + 3 * 16 + fr] = o3;
    }
    rnext[base + 0 * 16 + fr] = (unsigned short)bf16rne(fmaxf((o0 - mu) * rs * gv[0] + bv[0], 0.f));
    rnext[base + 1 * 16 + fr] = (unsigned short)bf16rne(fmaxf((o1 - mu) * rs * gv[1] + bv[1], 0.f));
    rnext[base + 2 * 16 + fr] = (unsigned short)bf16rne(fmaxf((o2 - mu) * rs * gv[2] + bv[2], 0.f));
    rnext[base + 3 * 16 + fr] = (unsigned short)bf16rne(fmaxf((o3 - mu) * rs * gv[3] + bv[3], 0.f));
  }
}

// ---------------- final via MFMA: out = rB @ lin_W + lin_b ------------------
// R13-proven, unchanged.

__global__ __launch_bounds__(256, 2) void k_final(const unsigned* __restrict__ rB32,
                                                  const unsigned* __restrict__ Wp,
                                                  const float* __restrict__ bias,
                                                  float* __restrict__ out) {
  int t = threadIdx.x;
  int w = t >> 6, lane = t & 63;
  int wid = blockIdx.x * 4 + w;
  if (wid >= N_NODES / 16) return;
  int node0 = wid * 16;
  int fr = lane & 15, fq = lane >> 4;
  bf16x8 xa0 = *(const bf16x8*)&rB32[(size_t)(node0 + fr) * 32 + fq * 4];
  bf16x8 xa1 = *(const bf16x8*)&rB32[(size_t)(node0 + fr) * 32 + 16 + fq * 4];
#pragma unroll
  for (int nt = 0; nt < 7; nt++) {
    f32x4 a = {0.f, 0.f, 0.f, 0.f};
    bf16x8 w0 = *(const bf16x8*)&Wp[(size_t)(nt * 16 + fr) * 36 + fq * 4];
    bf16x8 w1 = *(const bf16x8*)&Wp[(size_t)(nt * 16 + fr) * 36 + 16 + fq * 4];
    a = __builtin_amdgcn_mfma_f32_16x16x32_bf16(xa0, w0, a, 0, 0, 0);
    a = __builtin_amdgcn_mfma_f32_16x16x32_bf16(xa1, w1, a, 0, 0, 0);
    float bv = bias[nt * 16 + fr];
#pragma unroll
    for (int r = 0; r < 4; r++)
      out[(size_t)(node0 + fq * 4 + r) * DIM_OUT + nt * 16 + fr] = a[r] + bv;
  }
}

// ---------------- launch ----------------

extern "C" void kernel_launch(void* const* d_in, const int* in_sizes, int n_in,
                              void* d_out, int out_size, void* d_ws, size_t ws_size,
                              hipStream_t stream) {
  const float* x = (const float*)d_in[0];
  const int* ei = (const int*)d_in[1];
  const float* encW = (const float*)d_in[2];
  const float* encb = (const float*)d_in[3];
  const float* t_arr = (const float*)d_in[4];
  const float* sc_arr = (const float*)d_in[5];
  const float* W1 = (const float*)d_in[6];
  const float* b1 = (const float*)d_in[7];
  const float* g1 = (const float*)d_in[8];
  const float* bb1 = (const float*)d_in[9];
  const float* W2 = (const float*)d_in[10];
  const float* b2 = (const float*)d_in[11];
  const float* ng = (const float*)d_in[12];
  const float* nbias = (const float*)d_in[13];
  const float* linW = (const float*)d_in[14];
  const float* linb = (const float*)d_in[15];

  float* hA = (float*)d_ws;                                             // N*64 f32 h-state
  unsigned short* mCbf = (unsigned short*)(hA + (size_t)N_NODES * DIM_H);  // N*64 bf16 edge-out
  unsigned short* rBf = mCbf + (size_t)N_NODES * DIM_H;                 // N*64 bf16
  unsigned short* hBf = rBf + (size_t)N_NODES * DIM_H;                  // N*64 bf16
  int* ssrc = (int*)(hBf + (size_t)N_NODES * DIM_H);                    // E
  int* rank = ssrc + N_EDGES;                                           // E
  int* offs = rank + N_EDGES;                                           // N+1
  int* perm = offs + (N_NODES + 1);                                     // N
  int* counts = perm + N_NODES;                                         // N
  int* bsums = counts + N_NODES;                                        // <=512
  int* dbuck = bsums + 512;                                             // 64
  int* dcursor = dbuck + 64;                                            // 64
  unsigned* W1p = (unsigned*)(((uintptr_t)(dcursor + 64) + 15) & ~(uintptr_t)15);
  unsigned* W2p = W1p + (size_t)N_LAYERS * W1P_SZ;
  unsigned* Wep = W2p + (size_t)N_LAYERS * W2P_SZ;
  unsigned* Wfp = Wep + WEP_SZ;

  const int* srcI = ei;
  const int* dstI = ei + N_EDGES;

  const int nbScan = (N_NODES + 255) / 256;   // 391
  const int nbEdge = (N_EDGES + 255) / 256;   // 4688
  const int nbWave = (N_NODES / 16 + 3) / 4;  // 1563 blocks of 4 waves

  // CSR build (rank-based) + weight pre-pack
  k_zero_i<<<nbScan, 256, 0, stream>>>(counts, N_NODES);
  k_zero_i<<<1, 256, 0, stream>>>(dbuck, 64);
  k_hist<<<nbEdge, 256, 0, stream>>>(dstI, counts, rank);
  k_prepack<<<dim3(3, N_LAYERS), 256, 0, stream>>>(W1, W2, W1p, W2p);
  k_prepack_enc<<<3, 256, 0, stream>>>(encW, Wep);
  k_prepack_fin<<<3, 256, 0, stream>>>(linW, Wfp);
  k_scan1<<<nbScan, 256, 0, stream>>>(counts, bsums);
  k_scan2<<<1, 512, 0, stream>>>(bsums, nbScan);
  k_scan3<<<nbScan, 256, 0, stream>>>(counts, bsums, offs);
  k_scatter<<<nbEdge, 256, 0, stream>>>(srcI, dstI, rank, offs, ssrc);
  // degree-sorted perm (quartets of equal degree in k_edge)
  k_dhist<<<nbScan, 256, 0, stream>>>(offs, dbuck);
  k_dscan<<<1, 64, 0, stream>>>(dbuck, dcursor);
  k_dscatter<<<nbScan, 256, 0, stream>>>(offs, dcursor, perm);

  // encoder (MFMA) -> hBf (bf16)
  k_encoder<<<N_NODES / 32, 256, 0, stream>>>(x, Wep, encb, hBf);

  // layers 0..6: gather(uint2, degree-matched quartets) -> mCbf -> MFMA MLP
  for (int i = 0; i < N_LAYERS; i++) {
    int nx = (i + 1 < N_LAYERS) ? (i + 1) : 0;
    const unsigned* gin32 = (const unsigned*)((i == 0) ? hBf : rBf);
    if (i == 0)
      k_edge<1><<<N_NODES / 16, 256, 0, stream>>>(gin32, ssrc, offs, perm, t_arr, sc_arr,
                                                  i, (uint2*)mCbf);
    else
      k_edge<0><<<N_NODES / 16, 256, 0, stream>>>(gin32, ssrc, offs, perm, t_arr, sc_arr,
                                                  i, (uint2*)mCbf);
    if (i < N_LAYERS - 1)
      k_mlp<0><<<nbWave, 256, 0, stream>>>(
          (const unsigned*)mCbf, hA, rBf, W1p + (size_t)i * W1P_SZ, b1 + i * DIM_H2,
          g1 + i * DIM_H2, bb1 + i * DIM_H2, W2p + (size_t)i * W2P_SZ, b2 + i * DIM_H,
          ng + nx * DIM_H, nbias + nx * DIM_H, (i > 0) ? 1 : 0);
    else
      k_mlp<1><<<nbWave, 256, 0, stream>>>(
          (const unsigned*)mCbf, hA, rBf, W1p + (size_t)i * W1P_SZ, b1 + i * DIM_H2,
          g1 + i * DIM_H2, bb1 + i * DIM_H2, W2p + (size_t)i * W2P_SZ, b2 + i * DIM_H,
          ng + nx * DIM_H, nbias + nx * DIM_H, 1);
  }

  // final: rBf = bf16(relu(LN(h, nrm_0))); MFMA GEMM straight to out
  k_final<<<nbWave, 256, 0, stream>>>((const unsigned*)rBf, Wfp, linb, (float*)d_out);
}

// Round 22
// 511.274 us; speedup vs baseline: 1.3466x; 1.0233x over previous
//
#include <hip/hip_runtime.h>

#define N_NODES 100000
#define N_EDGES 1200000
#define DIM_IN 128
#define DIM_H 64
#define DIM_H2 128
#define DIM_OUT 112
#define N_LAYERS 7

// pre-packed weight sizes (uints), padded strides baked in
#define W1P_SZ 4608  // 128 n * 36 kp-stride (kp<32 valid)
#define W2P_SZ 4352  // 64 n * 68 kp-stride (kp<64 valid)
#define WEP_SZ 4352  // encoder: 64 n * 68 kp-stride (kp<64 valid)
#define WFP_SZ 4032  // final: 112 n * 36 kp-stride (kp<32 valid)

typedef __attribute__((ext_vector_type(8))) short bf16x8;
typedef __attribute__((ext_vector_type(4))) float f32x4;

// bf16 pack/unpack: bf16->f32 is just <<16 (bit ops, no cvt instruction)
__device__ __forceinline__ unsigned bf16rne(float f) {
  unsigned u = __float_as_uint(f);
  return (u + 0x7fffu + ((u >> 16) & 1u)) >> 16;
}
__device__ __forceinline__ unsigned pack2bf(float lo, float hi) {
  return bf16rne(lo) | (bf16rne(hi) << 16);
}
__device__ __forceinline__ float bflo(unsigned p) { return __uint_as_float(p << 16); }
__device__ __forceinline__ float bfhi(unsigned p) { return __uint_as_float(p & 0xffff0000u); }
// raw v_exp_f32 (2^x); __exp2f does not exist in HIP device code (R14 lesson)
__device__ __forceinline__ float exp2r(float x) { return __builtin_amdgcn_exp2f(x); }

// ---------------- preprocessing: CSR build (rank-based) ----------------
// R17/R20 lessons: returning atomicAdd ~35B/op memory-side regardless of
// sharding or line padding; exactly one returning-atomic pass is needed for
// any CSR build, so ~49us is this approach's floor (radix sort parked).

__global__ void k_zero_i(int* __restrict__ p, int n) {
  int i = blockIdx.x * 256 + threadIdx.x;
  if (i < n) p[i] = 0;
}

__global__ void k_hist(const int* __restrict__ dst, int* __restrict__ counts,
                       int* __restrict__ rank) {
  int e = blockIdx.x * 256 + threadIdx.x;
  if (e < N_EDGES) rank[e] = atomicAdd(&counts[dst[e]], 1);
}

__global__ void k_scan1(const int* __restrict__ counts, int* __restrict__ bsums) {
  __shared__ int sd[256];
  int t = threadIdx.x;
  int i = blockIdx.x * 256 + t;
  sd[t] = (i < N_NODES) ? counts[i] : 0;
  __syncthreads();
  for (int s = 128; s > 0; s >>= 1) {
    if (t < s) sd[t] += sd[t + s];
    __syncthreads();
  }
  if (t == 0) bsums[blockIdx.x] = sd[0];
}

__global__ void k_scan2(int* __restrict__ bsums, int nb) {
  __shared__ int sd[512];
  int t = threadIdx.x;
  int v = (t < nb) ? bsums[t] : 0;
  sd[t] = v;
  __syncthreads();
  for (int o = 1; o < 512; o <<= 1) {
    int add = (t >= o) ? sd[t - o] : 0;
    __syncthreads();
    sd[t] += add;
    __syncthreads();
  }
  if (t < nb) bsums[t] = sd[t] - v;  // exclusive
}

__global__ void k_scan3(const int* __restrict__ counts, const int* __restrict__ bsums,
                        int* __restrict__ offs) {
  __shared__ int sd[256];
  int t = threadIdx.x;
  int i = blockIdx.x * 256 + t;
  int v = (i < N_NODES) ? counts[i] : 0;
  sd[t] = v;
  __syncthreads();
  for (int o = 1; o < 256; o <<= 1) {
    int add = (t >= o) ? sd[t - o] : 0;
    __syncthreads();
    sd[t] += add;
    __syncthreads();
  }
  int excl = sd[t] - v + bsums[blockIdx.x];
  if (i < N_NODES) offs[i] = excl;
  if (i == N_NODES - 1) offs[N_NODES] = excl + v;  // = E
}

// atomic-free scatter: position = offs[dst] + rank.
__global__ void k_scatter(const int* __restrict__ src, const int* __restrict__ dst,
                          const int* __restrict__ rank, const int* __restrict__ offs,
                          int* __restrict__ ssrc) {
  int e = blockIdx.x * 256 + threadIdx.x;
  if (e < N_EDGES) {
    int p = offs[dst[e]] + rank[e];
    ssrc[p] = src[e];
  }
}

// ---------------- degree-sorted node permutation (R20-proven) ---------------
// Equal-degree nodes share a wave -> no quartet divergence in k_edge.

__global__ void k_dhist(const int* __restrict__ offs, int* __restrict__ dbuck) {
  __shared__ int lh[64];
  int t = threadIdx.x;
  int i = blockIdx.x * 256 + t;
  if (t < 64) lh[t] = 0;
  __syncthreads();
  if (i < N_NODES) {
    int deg = offs[i + 1] - offs[i];
    atomicAdd(&lh[min(deg, 63)], 1);
  }
  __syncthreads();
  if (t < 64 && lh[t]) atomicAdd(&dbuck[t], lh[t]);
}

__global__ void k_dscan(const int* __restrict__ dbuck, int* __restrict__ dcursor) {
  __shared__ int sd[64];
  int t = threadIdx.x;  // 1 block, 64 threads
  int v = dbuck[t];
  sd[t] = v;
  __syncthreads();
  for (int o = 1; o < 64; o <<= 1) {
    int add = (t >= o) ? sd[t - o] : 0;
    __syncthreads();
    sd[t] += add;
    __syncthreads();
  }
  dcursor[t] = sd[t] - v;  // exclusive
}

__global__ void k_dscatter(const int* __restrict__ offs, int* __restrict__ dcursor,
                           int* __restrict__ perm) {
  __shared__ int lh[64], lbase[64];
  int t = threadIdx.x;
  int i = blockIdx.x * 256 + t;
  if (t < 64) lh[t] = 0;
  __syncthreads();
  int b = 0, lr = 0;
  if (i < N_NODES) {
    int deg = offs[i + 1] - offs[i];
    b = min(deg, 63);
    lr = atomicAdd(&lh[b], 1);
  }
  __syncthreads();
  if (t < 64) lbase[t] = lh[t] ? atomicAdd(&dcursor[t], lh[t]) : 0;
  __syncthreads();
  if (i < N_NODES) perm[lbase[b] + lr] = i;
}

// ---------------- weight pre-pack (one kernel, gridDim.y = 8) ---------------
// y<7: layer weights; y==7: encoder + final weights.

__global__ void k_prepack_all(const float* __restrict__ W1, const float* __restrict__ W2,
                              const float* __restrict__ We, const float* __restrict__ Wf,
                              unsigned* __restrict__ W1p, unsigned* __restrict__ W2p,
                              unsigned* __restrict__ Wep, unsigned* __restrict__ Wfp) {
  int L = blockIdx.y;
  if (L < N_LAYERS) {
    const float* w1 = W1 + (size_t)L * DIM_H * DIM_H2;
    const float* w2 = W2 + (size_t)L * DIM_H2 * DIM_H;
    unsigned* o1 = W1p + (size_t)L * W1P_SZ;
    unsigned* o2 = W2p + (size_t)L * W2P_SZ;
    for (int i = blockIdx.x * 256 + threadIdx.x; i < W1P_SZ; i += gridDim.x * 256) {
      int n = i / 36, kp = i - n * 36;
      o1[i] = (kp < 32) ? pack2bf(w1[(size_t)(2 * kp) * DIM_H2 + n],
                                  w1[(size_t)(2 * kp + 1) * DIM_H2 + n]) : 0u;
    }
    for (int i = blockIdx.x * 256 + threadIdx.x; i < W2P_SZ; i += gridDim.x * 256) {
      int n = i / 68, kp = i - n * 68;
      o2[i] = (kp < 64) ? pack2bf(w2[(size_t)(2 * kp) * DIM_H + n],
                                  w2[(size_t)(2 * kp + 1) * DIM_H + n]) : 0u;
    }
  } else {
    for (int i = blockIdx.x * 256 + threadIdx.x; i < WEP_SZ; i += gridDim.x * 256) {
      int n = i / 68, kp = i - n * 68;
      Wep[i] = (kp < 64) ? pack2bf(We[(size_t)(2 * kp) * DIM_H + n],
                                   We[(size_t)(2 * kp + 1) * DIM_H + n]) : 0u;
    }
    for (int i = blockIdx.x * 256 + threadIdx.x; i < WFP_SZ; i += gridDim.x * 256) {
      int n = i / 36, kp = i - n * 36;
      Wfp[i] = (kp < 32) ? pack2bf(Wf[(size_t)(2 * kp) * DIM_OUT + n],
                                   Wf[(size_t)(2 * kp + 1) * DIM_OUT + n]) : 0u;
    }
  }
}

// ---------------- encoder via MFMA: hBf = bf16(x @ enc_W + enc_b) ----------
// R12-proven, unchanged.

__global__ __launch_bounds__(256, 2) void k_encoder(const float* __restrict__ x,
                                                    const unsigned* __restrict__ Wp,
                                                    const float* __restrict__ bias,
                                                    unsigned short* __restrict__ hBf) {
  __shared__ __attribute__((aligned(16))) unsigned sW[WEP_SZ];    // 17.4KB [n<64][kp<64] s68
  __shared__ __attribute__((aligned(16))) unsigned sxp[32 * 68];  // 8.7KB [row][kp<64] s68
  int t = threadIdx.x;
  int node0 = blockIdx.x * 32;
  int w = t >> 6, lane = t & 63;
  int fr = lane & 15, fq = lane >> 4;
  const uint4* wv4 = (const uint4*)Wp;
  for (int i = t; i < WEP_SZ / 4; i += 256) *(uint4*)&sW[i * 4] = wv4[i];
  for (int i = t; i < 2048; i += 256) {  // 32 rows x 64 kp
    int row = i >> 6, kp = i & 63;
    float2 xv = *(const float2*)&x[(size_t)(node0 + row) * DIM_IN + 2 * kp];
    sxp[row * 68 + kp] = pack2bf(xv.x, xv.y);
  }
  __syncthreads();
  f32x4 acc0 = {0.f, 0.f, 0.f, 0.f}, acc1 = acc0;
#pragma unroll
  for (int s = 0; s < 4; s++) {
    int kp0 = s * 16 + fq * 4;
    bf16x8 a0 = *(const bf16x8*)&sxp[fr * 68 + kp0];
    bf16x8 a1 = *(const bf16x8*)&sxp[(16 + fr) * 68 + kp0];
    bf16x8 wf = *(const bf16x8*)&sW[(w * 16 + fr) * 68 + kp0];
    acc0 = __builtin_amdgcn_mfma_f32_16x16x32_bf16(a0, wf, acc0, 0, 0, 0);
    acc1 = __builtin_amdgcn_mfma_f32_16x16x32_bf16(a1, wf, acc1, 0, 0, 0);
  }
  float bv = bias[w * 16 + fr];
#pragma unroll
  for (int r = 0; r < 4; r++) {
    hBf[(size_t)(node0 + fq * 4 + r) * DIM_H + w * 16 + fr] =
        (unsigned short)bf16rne(acc0[r] + bv);
    hBf[(size_t)(node0 + 16 + fq * 4 + r) * DIM_H + w * 16 + fr] =
        (unsigned short)bf16rne(acc1[r] + bv);
  }
}

// ---------------- edge aggregation + MsgNorm (uint2, ssrc-broadcast) --------
// Quarter-wave per node (R21-proven). NEW: in the 8-edge chunk, lanes 0-7 of
// each quarter load 8 edge indices in ONE vmem op; indices broadcast via
// __shfl (LDS pipe) -> VMEM instr per chunk 16 -> 9.

template <int RELU>
__global__ __launch_bounds__(256) void k_edge(const unsigned* __restrict__ xin32,
                                              const int* __restrict__ ssrc,
                                              const int* __restrict__ offs,
                                              const int* __restrict__ perm,
                                              const float* __restrict__ t_arr,
                                              const float* __restrict__ sc_arr, int layer,
                                              uint2* __restrict__ hmid2) {
  int t = threadIdx.x;
  int wave = t >> 6, lane = t & 63;
  int q = lane >> 4, cl = lane & 15;
  int gid = blockIdx.x * 16 + wave * 4 + q;
  int v = perm[gid];
  float c2 = t_arr[layer] * 1.4426950408889634f;  // t * log2(e)
  float sc = sc_arr[layer];
  int beg = offs[v], end = offs[v + 1];
  unsigned cl8 = cl << 3;
  int qbase = q << 4;
  const char* xbase = (const char*)xin32;
  uint2 xp = *(const uint2*)(xbase + (((unsigned)v << 7) + cl8));
  f32x4 xv = {bflo(xp.x), bfhi(xp.x), bflo(xp.y), bfhi(xp.y)};
  f32x4 Dv0 = {0.f, 0.f, 0.f, 0.f}, Dv1 = Dv0, Dv2 = Dv0, Dv3 = Dv0;
  f32x4 Sv0 = Dv0, Sv1 = Dv0, Sv2 = Dv0, Sv3 = Dv0;
  int e = beg;
#define UNPK4(u, m)                                      \
  f32x4 m;                                               \
  m.x = RELU ? fmaxf(bflo(u.x), 0.f) : bflo(u.x);        \
  m.y = RELU ? fmaxf(bfhi(u.x), 0.f) : bfhi(u.x);        \
  m.z = RELU ? fmaxf(bflo(u.y), 0.f) : bflo(u.y);        \
  m.w = RELU ? fmaxf(bfhi(u.y), 0.f) : bfhi(u.y);
#define EXPV4(m, ev)                                     \
  f32x4 ev;                                              \
  ev.x = exp2r(c2 * m.x);                                \
  ev.y = exp2r(c2 * m.y);                                \
  ev.z = exp2r(c2 * m.z);                                \
  ev.w = exp2r(c2 * m.w);
  for (; e + 7 < end; e += 8) {
    int eidx = ssrc[e + (cl & 7)];  // one vmem op serves 8 edges per quarter
    int s0 = __shfl(eidx, qbase + 0, 64);
    int s1 = __shfl(eidx, qbase + 1, 64);
    int s2 = __shfl(eidx, qbase + 2, 64);
    int s3 = __shfl(eidx, qbase + 3, 64);
    int s4 = __shfl(eidx, qbase + 4, 64);
    int s5 = __shfl(eidx, qbase + 5, 64);
    int s6 = __shfl(eidx, qbase + 6, 64);
    int s7 = __shfl(eidx, qbase + 7, 64);
    uint2 u0 = *(const uint2*)(xbase + (((unsigned)s0 << 7) + cl8));
    uint2 u1 = *(const uint2*)(xbase + (((unsigned)s1 << 7) + cl8));
    uint2 u2 = *(const uint2*)(xbase + (((unsigned)s2 << 7) + cl8));
    uint2 u3 = *(const uint2*)(xbase + (((unsigned)s3 << 7) + cl8));
    uint2 u4 = *(const uint2*)(xbase + (((unsigned)s4 << 7) + cl8));
    uint2 u5 = *(const uint2*)(xbase + (((unsigned)s5 << 7) + cl8));
    uint2 u6 = *(const uint2*)(xbase + (((unsigned)s6 << 7) + cl8));
    uint2 u7 = *(const uint2*)(xbase + (((unsigned)s7 << 7) + cl8));
    UNPK4(u0, m0) UNPK4(u1, m1) UNPK4(u2, m2) UNPK4(u3, m3)
    UNPK4(u4, m4) UNPK4(u5, m5) UNPK4(u6, m6) UNPK4(u7, m7)
    EXPV4(m0, e0) EXPV4(m1, e1) EXPV4(m2, e2) EXPV4(m3, e3)
    EXPV4(m4, e4) EXPV4(m5, e5) EXPV4(m6, e6) EXPV4(m7, e7)
    Dv0 += e0; Sv0 += m0 * e0;
    Dv1 += e1; Sv1 += m1 * e1;
    Dv2 += e2; Sv2 += m2 * e2;
    Dv3 += e3; Sv3 += m3 * e3;
    Dv0 += e4; Sv0 += m4 * e4;
    Dv1 += e5; Sv1 += m5 * e5;
    Dv2 += e6; Sv2 += m6 * e6;
    Dv3 += e7; Sv3 += m7 * e7;
  }
  if (e + 3 < end) {
    unsigned o0 = ((unsigned)ssrc[e] << 7) + cl8;
    unsigned o1 = ((unsigned)ssrc[e + 1] << 7) + cl8;
    unsigned o2 = ((unsigned)ssrc[e + 2] << 7) + cl8;
    unsigned o3 = ((unsigned)ssrc[e + 3] << 7) + cl8;
    uint2 u0 = *(const uint2*)(xbase + o0);
    uint2 u1 = *(const uint2*)(xbase + o1);
    uint2 u2 = *(const uint2*)(xbase + o2);
    uint2 u3 = *(const uint2*)(xbase + o3);
    UNPK4(u0, m0) UNPK4(u1, m1) UNPK4(u2, m2) UNPK4(u3, m3)
    EXPV4(m0, e0) EXPV4(m1, e1) EXPV4(m2, e2) EXPV4(m3, e3)
    Dv0 += e0; Sv0 += m0 * e0;
    Dv1 += e1; Sv1 += m1 * e1;
    Dv2 += e2; Sv2 += m2 * e2;
    Dv3 += e3; Sv3 += m3 * e3;
    e += 4;
  }
  for (; e < end; ++e) {
    unsigned o0 = ((unsigned)ssrc[e] << 7) + cl8;
    uint2 u0 = *(const uint2*)(xbase + o0);
    UNPK4(u0, m0)
    EXPV4(m0, e0)
    Dv0 += e0; Sv0 += m0 * e0;
  }
#undef UNPK4
#undef EXPV4
  f32x4 Dt = (Dv0 + Dv1) + (Dv2 + Dv3);
  f32x4 St = (Sv0 + Sv1) + (Sv2 + Sv3);
  int has = (end > beg);
  f32x4 agg;
  agg.x = has ? (St.x / Dt.x + 1e-7f) : 0.f;
  agg.y = has ? (St.y / Dt.y + 1e-7f) : 0.f;
  agg.z = has ? (St.z / Dt.z + 1e-7f) : 0.f;
  agg.w = has ? (St.w / Dt.w + 1e-7f) : 0.f;
  float na = (agg.x * agg.x + agg.y * agg.y) + (agg.z * agg.z + agg.w * agg.w);
  float nx = (xv.x * xv.x + xv.y * xv.y) + (xv.z * xv.z + xv.w * xv.w);
#pragma unroll
  for (int m = 1; m < 16; m <<= 1) {
    na += __shfl_xor(na, m, 64);
    nx += __shfl_xor(nx, m, 64);
  }
  float inv = sc * sqrtf(nx) / fmaxf(sqrtf(na), 1e-12f);
  uint2 outp;
  outp.x = pack2bf(xv.x + inv * agg.x, xv.y + inv * agg.y);
  outp.y = pack2bf(xv.z + inv * agg.z, xv.w + inv * agg.w);
  hmid2[(size_t)v * 16 + cl] = outp;
}

// ---------------- GENConv MLP: wave-autonomous, barrier-free MFMA ----------
// R13-proven. LAST=1 (layer 6): h dead after -> skip the 25.6MB h store.

template <int LAST>
__global__ __launch_bounds__(256, 2) void k_mlp(const unsigned* __restrict__ xin32,
                                                float* __restrict__ h,
                                                unsigned short* __restrict__ rnext,
                                                const unsigned* __restrict__ W1p,
                                                const float* __restrict__ b1,
                                                const float* __restrict__ g1,
                                                const float* __restrict__ bb1,
                                                const unsigned* __restrict__ W2p,
                                                const float* __restrict__ b2,
                                                const float* __restrict__ gn,
                                                const float* __restrict__ bn, int residual) {
  __shared__ unsigned short scr[4][16][136];  // wave-private U scratch
  int t = threadIdx.x;
  int w = t >> 6, lane = t & 63;
  int wid = blockIdx.x * 4 + w;
  if (wid >= N_NODES / 16) return;  // 6250 waves exactly
  int node0 = wid * 16;
  int fr = lane & 15, fq = lane >> 4;

  // GEMM1: C1[16][128] = X[16][64] @ W1
  bf16x8 xa0 = *(const bf16x8*)&xin32[(size_t)(node0 + fr) * 32 + fq * 4];
  bf16x8 xa1 = *(const bf16x8*)&xin32[(size_t)(node0 + fr) * 32 + 16 + fq * 4];
  f32x4 c1[8];
#pragma unroll
  for (int nt = 0; nt < 8; nt++) {
    f32x4 a = {0.f, 0.f, 0.f, 0.f};
    bf16x8 w0 = *(const bf16x8*)&W1p[(size_t)(nt * 16 + fr) * 36 + fq * 4];
    bf16x8 w1 = *(const bf16x8*)&W1p[(size_t)(nt * 16 + fr) * 36 + 16 + fq * 4];
    a = __builtin_amdgcn_mfma_f32_16x16x32_bf16(xa0, w0, a, 0, 0, 0);
    a = __builtin_amdgcn_mfma_f32_16x16x32_bf16(xa1, w1, a, 0, 0, 0);
    c1[nt] = a;
  }
  // LN over 128 cols per row; lane holds C1[row=fq*4+r][col=nt*16+fr]
  float b1v[8], g1v[8], bb1v[8];
#pragma unroll
  for (int nt = 0; nt < 8; nt++) {
    b1v[nt] = b1[nt * 16 + fr];
    g1v[nt] = g1[nt * 16 + fr];
    bb1v[nt] = bb1[nt * 16 + fr];
  }
#pragma unroll
  for (int r = 0; r < 4; r++) {
    float s1 = 0.f, s2 = 0.f;
#pragma unroll
    for (int nt = 0; nt < 8; nt++) {
      float u = c1[nt][r] + b1v[nt];
      s1 += u;
      s2 += u * u;
    }
#pragma unroll
    for (int m = 1; m < 16; m <<= 1) {
      s1 += __shfl_xor(s1, m, 64);
      s2 += __shfl_xor(s2, m, 64);
    }
    float mu = s1 * (1.f / 128.f);
    float var = s2 * (1.f / 128.f) - mu * mu;
    float rs = rsqrtf(var + 1e-5f);
    int row = fq * 4 + r;
#pragma unroll
    for (int nt = 0; nt < 8; nt++) {
      float u = c1[nt][r] + b1v[nt];
      u = fmaxf((u - mu) * rs * g1v[nt] + bb1v[nt], 0.f);
      scr[w][row][nt * 16 + fr] = (unsigned short)bf16rne(u);
    }
  }
  // GEMM2: C2[16][64] = U[16][128] @ W2 (A-frag k = s*32+fq*8+e)
  bf16x8 ua[4];
#pragma unroll
  for (int s = 0; s < 4; s++) ua[s] = *(const bf16x8*)&scr[w][fr][s * 32 + fq * 8];
  f32x4 c2[4];
#pragma unroll
  for (int nt = 0; nt < 4; nt++) {
    f32x4 a = {0.f, 0.f, 0.f, 0.f};
#pragma unroll
    for (int s = 0; s < 4; s++) {
      bf16x8 wf = *(const bf16x8*)&W2p[(size_t)(nt * 16 + fr) * 68 + s * 16 + fq * 4];
      a = __builtin_amdgcn_mfma_f32_16x16x32_bf16(ua[s], wf, a, 0, 0, 0);
    }
    c2[nt] = a;
  }
  // epilogue: +b2 (+res) -> h f32 (skipped on LAST); prenorm -> rnext bf16
  float b2v[4], gv[4], bv[4];
#pragma unroll
  for (int nt = 0; nt < 4; nt++) {
    b2v[nt] = b2[nt * 16 + fr];
    gv[nt] = gn[nt * 16 + fr];
    bv[nt] = bn[nt * 16 + fr];
  }
#pragma unroll
  for (int r = 0; r < 4; r++) {
    int row = fq * 4 + r;
    size_t base = (size_t)(node0 + row) * DIM_H;
    float o0, o1, o2, o3, s1, s2;
    o0 = c2[0][r] + b2v[0];
    o1 = c2[1][r] + b2v[1];
    o2 = c2[2][r] + b2v[2];
    o3 = c2[3][r] + b2v[3];
    if (residual) {
      o0 += h[base + 0 * 16 + fr];
      o1 += h[base + 1 * 16 + fr];
      o2 += h[base + 2 * 16 + fr];
      o3 += h[base + 3 * 16 + fr];
    }
    s1 = (o0 + o1) + (o2 + o3);
    s2 = (o0 * o0 + o1 * o1) + (o2 * o2 + o3 * o3);
#pragma unroll
    for (int m = 1; m < 16; m <<= 1) {
      s1 += __shfl_xor(s1, m, 64);
      s2 += __shfl_xor(s2, m, 64);
    }
    float mu = s1 * (1.f / 64.f);
    float var = s2 * (1.f / 64.f) - mu * mu;
    float rs = rsqrtf(var + 1e-5f);
    if (!LAST) {
      h[base + 0 * 16 + fr] = o0;
      h[base + 1 * 16 + fr] = o1;
      h[base + 2 * 16 + fr] = o2;
      h[base + 3 * 16 + fr] = o3;
    }
    rnext[base + 0 * 16 + fr] = (unsigned short)bf16rne(fmaxf((o0 - mu) * rs * gv[0] + bv[0], 0.f));
    rnext[base + 1 * 16 + fr] = (unsigned short)bf16rne(fmaxf((o1 - mu) * rs * gv[1] + bv[1], 0.f));
    rnext[base + 2 * 16 + fr] = (unsigned short)bf16rne(fmaxf((o2 - mu) * rs * gv[2] + bv[2], 0.f));
    rnext[base + 3 * 16 + fr] = (unsigned short)bf16rne(fmaxf((o3 - mu) * rs * gv[3] + bv[3], 0.f));
  }
}

// ---------------- final via MFMA: out = rB @ lin_W + lin_b ------------------
// R13-proven, unchanged.

__global__ __launch_bounds__(256, 2) void k_final(const unsigned* __restrict__ rB32,
                                                  const unsigned* __restrict__ Wp,
                                                  const float* __restrict__ bias,
                                                  float* __restrict__ out) {
  int t = threadIdx.x;
  int w = t >> 6, lane = t & 63;
  int wid = blockIdx.x * 4 + w;
  if (wid >= N_NODES / 16) return;
  int node0 = wid * 16;
  int fr = lane & 15, fq = lane >> 4;
  bf16x8 xa0 = *(const bf16x8*)&rB32[(size_t)(node0 + fr) * 32 + fq * 4];
  bf16x8 xa1 = *(const bf16x8*)&rB32[(size_t)(node0 + fr) * 32 + 16 + fq * 4];
#pragma unroll
  for (int nt = 0; nt < 7; nt++) {
    f32x4 a = {0.f, 0.f, 0.f, 0.f};
    bf16x8 w0 = *(const bf16x8*)&Wp[(size_t)(nt * 16 + fr) * 36 + fq * 4];
    bf16x8 w1 = *(const bf16x8*)&Wp[(size_t)(nt * 16 + fr) * 36 + 16 + fq * 4];
    a = __builtin_amdgcn_mfma_f32_16x16x32_bf16(xa0, w0, a, 0, 0, 0);
    a = __builtin_amdgcn_mfma_f32_16x16x32_bf16(xa1, w1, a, 0, 0, 0);
    float bv = bias[nt * 16 + fr];
#pragma unroll
    for (int r = 0; r < 4; r++)
      out[(size_t)(node0 + fq * 4 + r) * DIM_OUT + nt * 16 + fr] = a[r] + bv;
  }
}

// ---------------- launch ----------------

extern "C" void kernel_launch(void* const* d_in, const int* in_sizes, int n_in,
                              void* d_out, int out_size, void* d_ws, size_t ws_size,
                              hipStream_t stream) {
  const float* x = (const float*)d_in[0];
  const int* ei = (const int*)d_in[1];
  const float* encW = (const float*)d_in[2];
  const float* encb = (const float*)d_in[3];
  const float* t_arr = (const float*)d_in[4];
  const float* sc_arr = (const float*)d_in[5];
  const float* W1 = (const float*)d_in[6];
  const float* b1 = (const float*)d_in[7];
  const float* g1 = (const float*)d_in[8];
  const float* bb1 = (const float*)d_in[9];
  const float* W2 = (const float*)d_in[10];
  const float* b2 = (const float*)d_in[11];
  const float* ng = (const float*)d_in[12];
  const float* nbias = (const float*)d_in[13];
  const float* linW = (const float*)d_in[14];
  const float* linb = (const float*)d_in[15];

  float* hA = (float*)d_ws;                                             // N*64 f32 h-state
  unsigned short* mCbf = (unsigned short*)(hA + (size_t)N_NODES * DIM_H);  // N*64 bf16 edge-out
  unsigned short* rBf = mCbf + (size_t)N_NODES * DIM_H;                 // N*64 bf16
  unsigned short* hBf = rBf + (size_t)N_NODES * DIM_H;                  // N*64 bf16
  int* ssrc = (int*)(hBf + (size_t)N_NODES * DIM_H);                    // E
  int* rank = ssrc + N_EDGES;                                           // E
  int* offs = rank + N_EDGES;                                           // N+1
  int* perm = offs + (N_NODES + 1);                                     // N
  int* counts = perm + N_NODES;                                         // N
  int* dbuck = counts + N_NODES;                                        // 64 (zeroed with counts)
  int* bsums = dbuck + 64;                                              // <=512
  int* dcursor = bsums + 512;                                           // 64
  unsigned* W1p = (unsigned*)(((uintptr_t)(dcursor + 64) + 15) & ~(uintptr_t)15);
  unsigned* W2p = W1p + (size_t)N_LAYERS * W1P_SZ;
  unsigned* Wep = W2p + (size_t)N_LAYERS * W2P_SZ;
  unsigned* Wfp = Wep + WEP_SZ;

  const int* srcI = ei;
  const int* dstI = ei + N_EDGES;

  const int nbScan = (N_NODES + 255) / 256;   // 391
  const int nbEdge = (N_EDGES + 255) / 256;   // 4688
  const int nbWave = (N_NODES / 16 + 3) / 4;  // 1563 blocks of 4 waves

  // CSR build (rank-based) + degree perm + weight pre-pack
  k_zero_i<<<(N_NODES + 64 + 255) / 256, 256, 0, stream>>>(counts, N_NODES + 64);
  k_hist<<<nbEdge, 256, 0, stream>>>(dstI, counts, rank);
  k_prepack_all<<<dim3(3, N_LAYERS + 1), 256, 0, stream>>>(W1, W2, encW, linW, W1p, W2p,
                                                           Wep, Wfp);
  k_scan1<<<nbScan, 256, 0, stream>>>(counts, bsums);
  k_scan2<<<1, 512, 0, stream>>>(bsums, nbScan);
  k_scan3<<<nbScan, 256, 0, stream>>>(counts, bsums, offs);
  k_scatter<<<nbEdge, 256, 0, stream>>>(srcI, dstI, rank, offs, ssrc);
  k_dhist<<<nbScan, 256, 0, stream>>>(offs, dbuck);
  k_dscan<<<1, 64, 0, stream>>>(dbuck, dcursor);
  k_dscatter<<<nbScan, 256, 0, stream>>>(offs, dcursor, perm);

  // encoder (MFMA) -> hBf (bf16)
  k_encoder<<<N_NODES / 32, 256, 0, stream>>>(x, Wep, encb, hBf);

  // layers 0..6: gather(uint2, degree-matched quartets) -> mCbf -> MFMA MLP
  for (int i = 0; i < N_LAYERS; i++) {
    int nx = (i + 1 < N_LAYERS) ? (i + 1) : 0;
    const unsigned* gin32 = (const unsigned*)((i == 0) ? hBf : rBf);
    if (i == 0)
      k_edge<1><<<N_NODES / 16, 256, 0, stream>>>(gin32, ssrc, offs, perm, t_arr, sc_arr,
                                                  i, (uint2*)mCbf);
    else
      k_edge<0><<<N_NODES / 16, 256, 0, stream>>>(gin32, ssrc, offs, perm, t_arr, sc_arr,
                                                  i, (uint2*)mCbf);
    if (i < N_LAYERS - 1)
      k_mlp<0><<<nbWave, 256, 0, stream>>>(
          (const unsigned*)mCbf, hA, rBf, W1p + (size_t)i * W1P_SZ, b1 + i * DIM_H2,
          g1 + i * DIM_H2, bb1 + i * DIM_H2, W2p + (size_t)i * W2P_SZ, b2 + i * DIM_H,
          ng + nx * DIM_H, nbias + nx * DIM_H, (i > 0) ? 1 : 0);
    else
      k_mlp<1><<<nbWave, 256, 0, stream>>>(
          (const unsigned*)mCbf, hA, rBf, W1p + (size_t)i * W1P_SZ, b1 + i * DIM_H2,
          g1 + i * DIM_H2, bb1 + i * DIM_H2, W2p + (size_t)i * W2P_SZ, b2 + i * DIM_H,
          ng + nx * DIM_H, nbias + nx * DIM_H, 1);
  }

  // final: rBf = bf16(relu(LN(h, nrm_0))); MFMA GEMM straight to out
  k_final<<<nbWave, 256, 0, stream>>>((const unsigned*)rBf, Wfp, linb, (float*)d_out);
}